// Round 5
// baseline (561.971 us; speedup 1.0000x reference)
//
#include <hip/hip_runtime.h>
#include <hip/hip_bf16.h>
#include <cmath>

typedef __bf16 bf16;
typedef __bf16 bf16x8 __attribute__((ext_vector_type(8)));
typedef __bf16 bf16x4 __attribute__((ext_vector_type(4)));
typedef float  f32x4  __attribute__((ext_vector_type(4)));

// Problem constants: B=2, S=2048, D=2048, H=16, DH=128, full rotary (128), scale=1/sqrt(128)

// ---------------- fp32 -> bf16 convert (3 tensors at once) ----------------
__global__ void cvt3_kernel(const float* __restrict__ a, const float* __restrict__ b,
                            const float* __restrict__ c,
                            bf16* __restrict__ oa, bf16* __restrict__ ob, bf16* __restrict__ oc) {
    int i = (blockIdx.x * 256 + threadIdx.x) * 4;   // 8192 blocks * 256 * 4 = 8388608
    float4 va = *(const float4*)(a + i);
    float4 vb = *(const float4*)(b + i);
    float4 vc = *(const float4*)(c + i);
    bf16x4 ra = { (bf16)va.x, (bf16)va.y, (bf16)va.z, (bf16)va.w };
    bf16x4 rb = { (bf16)vb.x, (bf16)vb.y, (bf16)vb.z, (bf16)vb.w };
    bf16x4 rc = { (bf16)vc.x, (bf16)vc.y, (bf16)vc.z, (bf16)vc.w };
    *(bf16x4*)(oa + i) = ra;
    *(bf16x4*)(ob + i) = rb;
    *(bf16x4*)(oc + i) = rc;
}

// ---- all 4 weight transposes in one dispatch: z<3 -> W_{QKV}(H,D,DH)->[h*128+e][d];
// ---- z==3 -> W_O(H,DH,D)->[d][h*128+e] ----
__global__ void wt4_kernel(const float* __restrict__ WQ, const float* __restrict__ WK,
                           const float* __restrict__ WV, const float* __restrict__ WO,
                           bf16* __restrict__ WQT, bf16* __restrict__ WKT,
                           bf16* __restrict__ WVT, bf16* __restrict__ WOT) {
    int z = blockIdx.y;
    int o = blockIdx.x * 256 + threadIdx.x;   // 4,194,304 = 2048*2048
    if (z < 3) {
        const float* W = (z == 0) ? WQ : (z == 1) ? WK : WV;
        bf16* Wt       = (z == 0) ? WQT : (z == 1) ? WKT : WVT;
        int d = o & 2047;
        int he = o >> 11;
        int e = he & 127, h = he >> 7;
        Wt[o] = (bf16)W[(h << 18) + (d << 7) + e];   // h*2048*128 + d*128 + e
    } else {
        int he = o & 2047;
        int d = o >> 11;
        WOT[o] = (bf16)WO[(he << 11) + d];
    }
}

// ---------------- fused QKV projection GEMM (z selects Q/K/V) ----------------
// A: [4096][2048] bf16. Bm: [2048][2048] bf16 K-contiguous. 128x128 tile.
// Wave n-tile remap: col = wn*32 + (nt&1)*16 + (nt>>1)*64 + l16 so that the rotary
// partner pair (e, e+64) lives in the same lane as acc[mt][nt] / acc[mt][nt+2].
// z=0: rotary+scale -> QB[bh][s][e]; z=1: rotary -> KB; z=2: +bias -> VT[bh][e][s].
__launch_bounds__(256)
__global__ void qkv_gemm_kernel(const bf16* __restrict__ XQ, const bf16* __restrict__ XK,
                                const bf16* __restrict__ XV,
                                const bf16* __restrict__ WQT, const bf16* __restrict__ WKT,
                                const bf16* __restrict__ WVT,
                                const float* __restrict__ bQ, const float* __restrict__ bK,
                                const float* __restrict__ bV,
                                bf16* __restrict__ QB, bf16* __restrict__ KB,
                                bf16* __restrict__ VT) {
    __shared__ __align__(16) bf16 As[128 * 32];
    __shared__ __align__(16) bf16 Bs[128 * 32];
    __shared__ __align__(16) bf16 Cs[64 * 136];   // V-transpose staging (17 KB)
    const int z = blockIdx.z;
    const bf16* A  = (z == 0) ? XQ  : (z == 1) ? XK  : XV;
    const bf16* Bm = (z == 0) ? WQT : (z == 1) ? WKT : WVT;
    const float* bias = (z == 0) ? bQ : (z == 1) ? bK : bV;

    const int tid = threadIdx.x;
    const int w = tid >> 6, lane = tid & 63;
    const int quad = lane >> 4, l16 = lane & 15;
    const int wm = w & 1, wn = w >> 1;
    const int m_base = blockIdx.x << 7, n_base = blockIdx.y << 7;

    const int srow = lane >> 2;           // 0..15
    const int scol = (lane & 3) << 3;     // 0,8,16,24
    const int ab0 = w * 2, ab1 = w * 2 + 1;
    const bf16* gA0 = A  + (long)(m_base + ab0 * 16 + srow) * 2048 + scol;
    const bf16* gA1 = A  + (long)(m_base + ab1 * 16 + srow) * 2048 + scol;
    const bf16* gB0 = Bm + (long)(n_base + ab0 * 16 + srow) * 2048 + scol;
    const bf16* gB1 = Bm + (long)(n_base + ab1 * 16 + srow) * 2048 + scol;
    bf16* lA0 = &As[ab0 * 512];
    bf16* lA1 = &As[ab1 * 512];
    bf16* lB0 = &Bs[ab0 * 512];
    bf16* lB1 = &Bs[ab1 * 512];

    f32x4 acc[4][4] = {};

    for (int k0 = 0; k0 < 2048; k0 += 32) {
        __builtin_amdgcn_global_load_lds((const __attribute__((address_space(1))) void*)(gA0 + k0),
                                         (__attribute__((address_space(3))) void*)lA0, 16, 0, 0);
        __builtin_amdgcn_global_load_lds((const __attribute__((address_space(1))) void*)(gA1 + k0),
                                         (__attribute__((address_space(3))) void*)lA1, 16, 0, 0);
        __builtin_amdgcn_global_load_lds((const __attribute__((address_space(1))) void*)(gB0 + k0),
                                         (__attribute__((address_space(3))) void*)lB0, 16, 0, 0);
        __builtin_amdgcn_global_load_lds((const __attribute__((address_space(1))) void*)(gB1 + k0),
                                         (__attribute__((address_space(3))) void*)lB1, 16, 0, 0);
        __syncthreads();

        bf16x8 af[4], bfr[4];
#pragma unroll
        for (int mt = 0; mt < 4; mt++)
            af[mt] = *(const bf16x8*)&As[((wm * 64 + mt * 16 + l16) << 5) + (quad << 3)];
#pragma unroll
        for (int nt = 0; nt < 4; nt++) {
            int nrow = wn * 32 + (nt & 1) * 16 + (nt >> 1) * 64 + l16;
            bfr[nt] = *(const bf16x8*)&Bs[(nrow << 5) + (quad << 3)];
        }
#pragma unroll
        for (int mt = 0; mt < 4; mt++)
#pragma unroll
            for (int nt = 0; nt < 4; nt++)
                acc[mt][nt] = __builtin_amdgcn_mfma_f32_16x16x32_bf16(af[mt], bfr[nt], acc[mt][nt], 0, 0, 0);
        __syncthreads();
    }

    const int bq = m_base >> 11;          // batch (whole block same batch)
    const int h  = n_base >> 7;           // head  (N-tile == head width)
    const long obase = ((long)(bq * 16 + h)) << 18;

    if (z <= 1) {
        // rotary epilogue, partner pair in-lane: acc[mt][nt] (e_lo) with acc[mt][nt+2] (e_lo+64)
        bf16* O = (z == 0) ? QB : KB;
        const float scl = (z == 0) ? 0.08838834764831845f : 1.0f;   // 1/sqrt(128) folded into Q
#pragma unroll
        for (int nt = 0; nt < 2; nt++) {
            const int e_lo = wn * 32 + nt * 16 + l16;               // 0..63
            const float bv_lo = bias[n_base + e_lo];
            const float bv_hi = bias[n_base + e_lo + 64];
            const float inv_freq = exp2f((float)e_lo * -0.20762050593046f);  // 10000^(-e/64)
#pragma unroll
            for (int mt = 0; mt < 4; mt++) {
#pragma unroll
                for (int r = 0; r < 4; r++) {
                    int s = (m_base & 2047) + wm * 64 + mt * 16 + quad * 4 + r;
                    float sn, cs;
                    __sincosf((float)s * inv_freq, &sn, &cs);
                    float x0 = acc[mt][nt][r]     + bv_lo;
                    float x1 = acc[mt][nt + 2][r] + bv_hi;
                    O[obase + ((long)s << 7) + e_lo]      = (bf16)((x0 * cs - x1 * sn) * scl);
                    O[obase + ((long)s << 7) + e_lo + 64] = (bf16)((x1 * cs + x0 * sn) * scl);
                }
            }
        }
    } else {
        // V: transpose 128x128 tile to VT[bh][e][s] via LDS, two e-halves of 64
#pragma unroll
        for (int eh = 0; eh < 2; eh++) {
#pragma unroll
            for (int nt2 = 0; nt2 < 2; nt2++) {
                const int nt = eh * 2 + nt2;
                const int e_l = wn * 32 + nt2 * 16 + l16;    // 0..63 local within half
                const float bv = bias[n_base + eh * 64 + e_l];
#pragma unroll
                for (int mt = 0; mt < 4; mt++) {
                    int s0 = wm * 64 + mt * 16 + quad * 4;
                    bf16x4 pk = { (bf16)(acc[mt][nt][0] + bv), (bf16)(acc[mt][nt][1] + bv),
                                  (bf16)(acc[mt][nt][2] + bv), (bf16)(acc[mt][nt][3] + bv) };
                    *(bf16x4*)&Cs[e_l * 136 + s0] = pk;
                }
            }
            __syncthreads();
            {
                const int e_l = tid >> 2;            // 0..63
                const int sq  = (tid & 3) << 5;      // 0,32,64,96
                const int e   = eh * 64 + e_l;
                const long vb = obase + ((long)e << 11) + (m_base & 2047) + sq;
#pragma unroll
                for (int j = 0; j < 4; j++)
                    *(bf16x8*)&VT[vb + j * 8] = *(const bf16x8*)&Cs[e_l * 136 + sq + j * 8];
            }
            __syncthreads();
        }
    }
}

// ---------------- causal flash attention ----------------
// Fixed-max softmax: p = exp(s - 12), e^-12 cancels in o/l. Per-lane l accumulates;
// one 4-shuffle reduce per q-tile. XCD-swizzled 1-D grid; paired q-tiles (qt=xb, 31-xb).
__launch_bounds__(256)
__global__ void flash_kernel(const bf16* __restrict__ Q, const bf16* __restrict__ K,
                             const bf16* __restrict__ Vt, bf16* __restrict__ Z) {
    __shared__ __align__(16) bf16 Ks[64 * 136];   // pad 128->136
    __shared__ __align__(16) bf16 Vs[128 * 72];   // pad 64->72, rows = e
    __shared__ __align__(16) bf16 Ps[64 * 72];    // per-wave-private 16-row regions
    const int tid = threadIdx.x, w = tid >> 6, lane = tid & 63;
    const int quad = lane >> 4, l16 = lane & 15;
    const int n = blockIdx.x;
    const int xb = n >> 5;
    const int bh = (((n >> 3) & 3) << 3) | (n & 7);
    const int b = bh >> 4, h = bh & 15;
    const long qk_base = (long)bh << 18;          // bh*2048*128
    const float FM = 12.0f;                       // fixed softmax max

    for (int half = 0; half < 2; half++) {
        const int qt = half ? (31 - xb) : xb;
        const int qbase = qt * 64;

        bf16x8 qf[4];
#pragma unroll
        for (int ks = 0; ks < 4; ks++)
            qf[ks] = *(const bf16x8*)(Q + qk_base + ((long)(qbase + w * 16 + l16) << 7) + ks * 32 + (quad << 3));

        f32x4 o[8] = {};
        float lsum[4] = {0.f, 0.f, 0.f, 0.f};

        for (int kt = 0; kt <= qt; kt++) {
#pragma unroll
            for (int p = 0; p < 4; p++) {   // stage K tile 64x128
                int t = p * 256 + tid;
                int row = t >> 4, col = (t & 15) << 3;
                *(bf16x8*)&Ks[row * 136 + col] = *(const bf16x8*)(K + qk_base + ((long)(kt * 64 + row) << 7) + col);
            }
#pragma unroll
            for (int p = 0; p < 4; p++) {   // stage V^T tile 128x64
                int t = p * 256 + tid;
                int row = t >> 3, col = (t & 7) << 3;
                *(bf16x8*)&Vs[row * 72 + col] = *(const bf16x8*)(Vt + qk_base + ((long)row << 11) + kt * 64 + col);
            }
            __syncthreads();

            f32x4 sc[4] = {};
#pragma unroll
            for (int nt = 0; nt < 4; nt++)
#pragma unroll
                for (int ks = 0; ks < 4; ks++) {
                    bf16x8 kf = *(const bf16x8*)&Ks[(nt * 16 + l16) * 136 + ks * 32 + (quad << 3)];
                    sc[nt] = __builtin_amdgcn_mfma_f32_16x16x32_bf16(qf[ks], kf, sc[nt], 0, 0, 0);
                }

            if (kt == qt) {   // diagonal tile: causal mask (exp underflows to exact 0)
#pragma unroll
                for (int nt = 0; nt < 4; nt++)
#pragma unroll
                    for (int r = 0; r < 4; r++) {
                        int qrow = qbase + w * 16 + quad * 4 + r;
                        int kv = kt * 64 + nt * 16 + l16;
                        if (kv > qrow) sc[nt][r] = -3.0e38f;
                    }
            }

            // p = exp(s - FM); accumulate per-lane row sums; write P to per-wave LDS region
#pragma unroll
            for (int nt = 0; nt < 4; nt++)
#pragma unroll
                for (int r = 0; r < 4; r++) {
                    float p = __expf(sc[nt][r] - FM);
                    lsum[r] += p;
                    Ps[(w * 16 + quad * 4 + r) * 72 + nt * 16 + l16] = (bf16)p;
                }
            // no barrier: Ps region is wave-private; in-wave lgkmcnt orders write->read

#pragma unroll
            for (int kk = 0; kk < 2; kk++) {
                bf16x8 pf = *(const bf16x8*)&Ps[(w * 16 + l16) * 72 + kk * 32 + (quad << 3)];
#pragma unroll
                for (int dt = 0; dt < 8; dt++) {
                    bf16x8 vf = *(const bf16x8*)&Vs[(dt * 16 + l16) * 72 + kk * 32 + (quad << 3)];
                    o[dt] = __builtin_amdgcn_mfma_f32_16x16x32_bf16(pf, vf, o[dt], 0, 0, 0);
                }
            }
            __syncthreads();   // protect Ks/Vs (and Ps) before next staging
        }

        // single end-of-tile reduction of l across the 16-lane row group
#pragma unroll
        for (int r = 0; r < 4; r++) {
            float l = lsum[r];
            l += __shfl_xor(l, 1);
            l += __shfl_xor(l, 2);
            l += __shfl_xor(l, 4);
            l += __shfl_xor(l, 8);
            float inv = 1.f / l;
            int qrow = qbase + w * 16 + quad * 4 + r;
            long zr = ((long)(b * 2048 + qrow) << 11) + h * 128;
#pragma unroll
            for (int dt = 0; dt < 8; dt++)
                Z[zr + dt * 16 + l16] = (bf16)(o[dt][r] * inv);
        }
    }
}

// ---------------- output projection GEMM, split-K x2 ----------------
// z = blockIdx.z selects K-half; partial fp32 written without bias.
// 1024 blocks restores the oversubscription the m97 structure needs (512-block
// dispatches measured ~260-300 TF vs 781 TF at 1536 blocks).
__launch_bounds__(256)
__global__ void gemm_o_kernel(const bf16* __restrict__ A, const bf16* __restrict__ Bm,
                              float* __restrict__ P0, float* __restrict__ P1) {
    __shared__ __align__(16) bf16 As[128 * 32];
    __shared__ __align__(16) bf16 Bs[128 * 32];
    const int tid = threadIdx.x;
    const int w = tid >> 6, lane = tid & 63;
    const int quad = lane >> 4, l16 = lane & 15;
    const int wm = w & 1, wn = w >> 1;
    const int m_base = blockIdx.x << 7, n_base = blockIdx.y << 7;
    const int kb = blockIdx.z << 10;            // 0 or 1024
    float* Of = blockIdx.z ? P1 : P0;

    const int srow = lane >> 2;
    const int scol = (lane & 3) << 3;
    const int ab0 = w * 2, ab1 = w * 2 + 1;
    const bf16* gA0 = A  + (long)(m_base + ab0 * 16 + srow) * 2048 + kb + scol;
    const bf16* gA1 = A  + (long)(m_base + ab1 * 16 + srow) * 2048 + kb + scol;
    const bf16* gB0 = Bm + (long)(n_base + ab0 * 16 + srow) * 2048 + kb + scol;
    const bf16* gB1 = Bm + (long)(n_base + ab1 * 16 + srow) * 2048 + kb + scol;
    bf16* lA0 = &As[ab0 * 512];
    bf16* lA1 = &As[ab1 * 512];
    bf16* lB0 = &Bs[ab0 * 512];
    bf16* lB1 = &Bs[ab1 * 512];

    f32x4 acc[4][4] = {};

    for (int k0 = 0; k0 < 1024; k0 += 32) {
        __builtin_amdgcn_global_load_lds((const __attribute__((address_space(1))) void*)(gA0 + k0),
                                         (__attribute__((address_space(3))) void*)lA0, 16, 0, 0);
        __builtin_amdgcn_global_load_lds((const __attribute__((address_space(1))) void*)(gA1 + k0),
                                         (__attribute__((address_space(3))) void*)lA1, 16, 0, 0);
        __builtin_amdgcn_global_load_lds((const __attribute__((address_space(1))) void*)(gB0 + k0),
                                         (__attribute__((address_space(3))) void*)lB0, 16, 0, 0);
        __builtin_amdgcn_global_load_lds((const __attribute__((address_space(1))) void*)(gB1 + k0),
                                         (__attribute__((address_space(3))) void*)lB1, 16, 0, 0);
        __syncthreads();

        bf16x8 af[4], bfr[4];
#pragma unroll
        for (int mt = 0; mt < 4; mt++)
            af[mt] = *(const bf16x8*)&As[((wm * 64 + mt * 16 + l16) << 5) + (quad << 3)];
#pragma unroll
        for (int nt = 0; nt < 4; nt++)
            bfr[nt] = *(const bf16x8*)&Bs[((wn * 64 + nt * 16 + l16) << 5) + (quad << 3)];
#pragma unroll
        for (int mt = 0; mt < 4; mt++)
#pragma unroll
            for (int nt = 0; nt < 4; nt++)
                acc[mt][nt] = __builtin_amdgcn_mfma_f32_16x16x32_bf16(af[mt], bfr[nt], acc[mt][nt], 0, 0, 0);
        __syncthreads();
    }

#pragma unroll
    for (int nt = 0; nt < 4; nt++) {
        int col = n_base + wn * 64 + nt * 16 + l16;
#pragma unroll
        for (int mt = 0; mt < 4; mt++) {
#pragma unroll
            for (int r = 0; r < 4; r++) {
                int row = m_base + wm * 64 + mt * 16 + quad * 4 + r;
                Of[((long)row << 11) + col] = acc[mt][nt][r];
            }
        }
    }
}

// ---------------- out = p0 + p1 + bias (fp32, float4) ----------------
__global__ void add2_kernel(const float* __restrict__ p0, const float* __restrict__ p1,
                            const float* __restrict__ bias, float* __restrict__ out) {
    int i = (blockIdx.x * 256 + threadIdx.x) * 4;   // 8192 blocks -> 8,388,608 elems
    float4 a = *(const float4*)(p0 + i);
    float4 b = *(const float4*)(p1 + i);
    float4 bv = *(const float4*)(bias + (i & 2047));
    float4 r = { a.x + b.x + bv.x, a.y + b.y + bv.y, a.z + b.z + bv.z, a.w + b.w + bv.w };
    *(float4*)(out + i) = r;
}

extern "C" void kernel_launch(void* const* d_in, const int* in_sizes, int n_in,
                              void* d_out, int out_size, void* d_ws, size_t ws_size,
                              hipStream_t stream) {
    (void)in_sizes; (void)n_in; (void)out_size; (void)ws_size;
    const float* qin = (const float*)d_in[0];
    const float* kin = (const float*)d_in[1];
    const float* vin = (const float*)d_in[2];
    const float* WQ  = (const float*)d_in[3];
    const float* WK  = (const float*)d_in[4];
    const float* WV  = (const float*)d_in[5];
    const float* WO  = (const float*)d_in[6];
    const float* bQ  = (const float*)d_in[7];
    const float* bK  = (const float*)d_in[8];
    const float* bV  = (const float*)d_in[9];
    const float* bO  = (const float*)d_in[10];
    float* out = (float*)d_out;

    bf16* ws = (bf16*)d_ws;
    bf16* XQ  = ws + 0L;          // 8,388,608 elems each
    bf16* XK  = ws + 8388608L;
    bf16* XV  = ws + 16777216L;
    bf16* WQT = ws + 25165824L;   // 4,194,304 each
    bf16* WKT = ws + 29360128L;
    bf16* WVT = ws + 33554432L;
    bf16* WOT = ws + 37748736L;
    bf16* QB  = ws + 41943040L;   // [bh][s][e]
    bf16* KB  = ws + 50331648L;   // [bh][s][e]
    bf16* VT  = ws + 58720256L;   // [bh][e][s]   total 67,108,864 elems = 128 MiB
    bf16* Z   = XQ;               // reuse: XQ dead after qkv_gemm dispatch completes
    // split-K partials (fp32, 8,388,608 floats each) over dead regions:
    float* P0 = (float*)(ws + 8388608L);    // XK+XV region (dead after qkv_gemm)
    float* P1 = (float*)(ws + 41943040L);   // QB+KB region (dead after flash)

    cvt3_kernel<<<8192, 256, 0, stream>>>(qin, kin, vin, XQ, XK, XV);
    wt4_kernel<<<dim3(16384, 4), 256, 0, stream>>>(WQ, WK, WV, WO, WQT, WKT, WVT, WOT);
    qkv_gemm_kernel<<<dim3(32, 16, 3), 256, 0, stream>>>(XQ, XK, XV, WQT, WKT, WVT,
                                                         bQ, bK, bV, QB, KB, VT);
    flash_kernel<<<512, 256, 0, stream>>>(QB, KB, VT, Z);
    gemm_o_kernel<<<dim3(32, 16, 2), 256, 0, stream>>>(Z, WOT, P0, P1);
    add2_kernel<<<8192, 256, 0, stream>>>(P0, P1, bO, out);
}

// Round 6
// 544.781 us; speedup vs baseline: 1.0316x; 1.0316x over previous
//
#include <hip/hip_runtime.h>
#include <hip/hip_bf16.h>
#include <cmath>

typedef __bf16 bf16;
typedef __bf16 bf16x8 __attribute__((ext_vector_type(8)));
typedef __bf16 bf16x4 __attribute__((ext_vector_type(4)));
typedef float  f32x4  __attribute__((ext_vector_type(4)));

// Problem constants: B=2, S=2048, D=2048, H=16, DH=128, full rotary (128), scale=1/sqrt(128)

// ---------------- merged preprocessing: X fp32->bf16 + all 4 weight transposes ----------------
// grid (16384, 5): y=0 -> convert qin/kin/vin (2 elems/thread each, float2);
// y=1..3 -> W_{QKV}(H,D,DH) -> [h*128+e][d] bf16; y=4 -> W_O(H,DH,D) -> [d][h*128+e] bf16.
__global__ void prep_kernel(const float* __restrict__ qin, const float* __restrict__ kin,
                            const float* __restrict__ vin,
                            const float* __restrict__ WQ, const float* __restrict__ WK,
                            const float* __restrict__ WV, const float* __restrict__ WO,
                            bf16* __restrict__ XQ, bf16* __restrict__ XK, bf16* __restrict__ XV,
                            bf16* __restrict__ WQT, bf16* __restrict__ WKT,
                            bf16* __restrict__ WVT, bf16* __restrict__ WOT) {
    int y = blockIdx.y;
    int o = blockIdx.x * 256 + threadIdx.x;       // 4,194,304 threads per plane
    if (y == 0) {
        int i = o * 2;                            // 8,388,608 elems per tensor
        float2 a = *(const float2*)(qin + i);
        float2 b = *(const float2*)(kin + i);
        float2 c = *(const float2*)(vin + i);
        bf16 ra[2] = { (bf16)a.x, (bf16)a.y };
        bf16 rb[2] = { (bf16)b.x, (bf16)b.y };
        bf16 rc[2] = { (bf16)c.x, (bf16)c.y };
        *(short*)&XQ[i] = *(short*)&ra[0]; *(short*)&XQ[i+1] = *(short*)&ra[1];
        *(short*)&XK[i] = *(short*)&rb[0]; *(short*)&XK[i+1] = *(short*)&rb[1];
        *(short*)&XV[i] = *(short*)&rc[0]; *(short*)&XV[i+1] = *(short*)&rc[1];
    } else if (y < 4) {
        const float* W = (y == 1) ? WQ : (y == 2) ? WK : WV;
        bf16* Wt       = (y == 1) ? WQT : (y == 2) ? WKT : WVT;
        int d = o & 2047;
        int he = o >> 11;
        int e = he & 127, h = he >> 7;
        Wt[o] = (bf16)W[(h << 18) + (d << 7) + e];   // h*2048*128 + d*128 + e
    } else {
        int he = o & 2047;
        int d = o >> 11;
        WOT[o] = (bf16)WO[(he << 11) + d];
    }
}

// ---------------- fused QKV projection GEMM (z selects Q/K/V), BK=64 ----------------
// A: [4096][2048] bf16. Bm: [2048][2048] bf16 K-contiguous. 128x128 tile.
// BK=64: two 16 KB half-buffers per operand, staged in one vmcnt batch -> half the
// barrier count (32 k-iters) vs BK=32. LDS reads per half identical to BK=32 layout.
// Wave n-tile remap: col = wn*32 + (nt&1)*16 + (nt>>1)*64 + l16 so the rotary partner
// pair (e, e+64) lives in the same lane as acc[mt][nt] / acc[mt][nt+2].
// z=0: rotary+scale -> QB[bh][s][e]; z=1: rotary -> KB; z=2: +bias -> VT[bh][e][s].
__launch_bounds__(256)
__global__ void qkv_gemm_kernel(const bf16* __restrict__ XQ, const bf16* __restrict__ XK,
                                const bf16* __restrict__ XV,
                                const bf16* __restrict__ WQT, const bf16* __restrict__ WKT,
                                const bf16* __restrict__ WVT,
                                const float* __restrict__ bQ, const float* __restrict__ bK,
                                const float* __restrict__ bV,
                                bf16* __restrict__ QB, bf16* __restrict__ KB,
                                bf16* __restrict__ VT) {
    __shared__ __align__(16) bf16 As[2][128 * 32];   // 16 KB (2 half-K buffers)
    __shared__ __align__(16) bf16 Bs[2][128 * 32];   // 16 KB
    __shared__ __align__(16) bf16 Cs[64 * 136];      // V-transpose staging (17 KB)
    const int z = blockIdx.z;
    const bf16* A  = (z == 0) ? XQ  : (z == 1) ? XK  : XV;
    const bf16* Bm = (z == 0) ? WQT : (z == 1) ? WKT : WVT;
    const float* bias = (z == 0) ? bQ : (z == 1) ? bK : bV;

    const int tid = threadIdx.x;
    const int w = tid >> 6, lane = tid & 63;
    const int quad = lane >> 4, l16 = lane & 15;
    const int wm = w & 1, wn = w >> 1;
    const int m_base = blockIdx.x << 7, n_base = blockIdx.y << 7;

    const int srow = lane >> 2;           // 0..15
    const int scol = (lane & 3) << 3;     // 0,8,16,24
    const int ab0 = w * 2, ab1 = w * 2 + 1;
    const bf16* gA0 = A  + (long)(m_base + ab0 * 16 + srow) * 2048 + scol;
    const bf16* gA1 = A  + (long)(m_base + ab1 * 16 + srow) * 2048 + scol;
    const bf16* gB0 = Bm + (long)(n_base + ab0 * 16 + srow) * 2048 + scol;
    const bf16* gB1 = Bm + (long)(n_base + ab1 * 16 + srow) * 2048 + scol;

    f32x4 acc[4][4] = {};

    for (int k0 = 0; k0 < 2048; k0 += 64) {
#pragma unroll
        for (int hf = 0; hf < 2; hf++) {
            const int ko = k0 + hf * 32;
            __builtin_amdgcn_global_load_lds((const __attribute__((address_space(1))) void*)(gA0 + ko),
                                             (__attribute__((address_space(3))) void*)&As[hf][ab0 * 512], 16, 0, 0);
            __builtin_amdgcn_global_load_lds((const __attribute__((address_space(1))) void*)(gA1 + ko),
                                             (__attribute__((address_space(3))) void*)&As[hf][ab1 * 512], 16, 0, 0);
            __builtin_amdgcn_global_load_lds((const __attribute__((address_space(1))) void*)(gB0 + ko),
                                             (__attribute__((address_space(3))) void*)&Bs[hf][ab0 * 512], 16, 0, 0);
            __builtin_amdgcn_global_load_lds((const __attribute__((address_space(1))) void*)(gB1 + ko),
                                             (__attribute__((address_space(3))) void*)&Bs[hf][ab1 * 512], 16, 0, 0);
        }
        __syncthreads();

#pragma unroll
        for (int hf = 0; hf < 2; hf++) {
            bf16x8 af[4], bfr[4];
#pragma unroll
            for (int mt = 0; mt < 4; mt++)
                af[mt] = *(const bf16x8*)&As[hf][((wm * 64 + mt * 16 + l16) << 5) + (quad << 3)];
#pragma unroll
            for (int nt = 0; nt < 4; nt++) {
                int nrow = wn * 32 + (nt & 1) * 16 + (nt >> 1) * 64 + l16;
                bfr[nt] = *(const bf16x8*)&Bs[hf][(nrow << 5) + (quad << 3)];
            }
#pragma unroll
            for (int mt = 0; mt < 4; mt++)
#pragma unroll
                for (int nt = 0; nt < 4; nt++)
                    acc[mt][nt] = __builtin_amdgcn_mfma_f32_16x16x32_bf16(af[mt], bfr[nt], acc[mt][nt], 0, 0, 0);
        }
        __syncthreads();
    }

    const int bq = m_base >> 11;          // batch (whole block same batch)
    const int h  = n_base >> 7;           // head  (N-tile == head width)
    const long obase = ((long)(bq * 16 + h)) << 18;

    if (z <= 1) {
        // rotary epilogue, partner pair in-lane: acc[mt][nt] (e_lo) with acc[mt][nt+2] (e_lo+64)
        bf16* O = (z == 0) ? QB : KB;
        const float scl = (z == 0) ? 0.08838834764831845f : 1.0f;   // 1/sqrt(128) folded into Q
#pragma unroll
        for (int nt = 0; nt < 2; nt++) {
            const int e_lo = wn * 32 + nt * 16 + l16;               // 0..63
            const float bv_lo = bias[n_base + e_lo];
            const float bv_hi = bias[n_base + e_lo + 64];
            const float inv_freq = exp2f((float)e_lo * -0.20762050593046f);  // 10000^(-e/64)
#pragma unroll
            for (int mt = 0; mt < 4; mt++) {
#pragma unroll
                for (int r = 0; r < 4; r++) {
                    int s = (m_base & 2047) + wm * 64 + mt * 16 + quad * 4 + r;
                    float sn, cs;
                    __sincosf((float)s * inv_freq, &sn, &cs);
                    float x0 = acc[mt][nt][r]     + bv_lo;
                    float x1 = acc[mt][nt + 2][r] + bv_hi;
                    O[obase + ((long)s << 7) + e_lo]      = (bf16)((x0 * cs - x1 * sn) * scl);
                    O[obase + ((long)s << 7) + e_lo + 64] = (bf16)((x1 * cs + x0 * sn) * scl);
                }
            }
        }
    } else {
        // V: transpose 128x128 tile to VT[bh][e][s] via LDS, two e-halves of 64
#pragma unroll
        for (int eh = 0; eh < 2; eh++) {
#pragma unroll
            for (int nt2 = 0; nt2 < 2; nt2++) {
                const int nt = eh * 2 + nt2;
                const int e_l = wn * 32 + nt2 * 16 + l16;    // 0..63 local within half
                const float bv = bias[n_base + eh * 64 + e_l];
#pragma unroll
                for (int mt = 0; mt < 4; mt++) {
                    int s0 = wm * 64 + mt * 16 + quad * 4;
                    bf16x4 pk = { (bf16)(acc[mt][nt][0] + bv), (bf16)(acc[mt][nt][1] + bv),
                                  (bf16)(acc[mt][nt][2] + bv), (bf16)(acc[mt][nt][3] + bv) };
                    *(bf16x4*)&Cs[e_l * 136 + s0] = pk;
                }
            }
            __syncthreads();
            {
                const int e_l = tid >> 2;            // 0..63
                const int sq  = (tid & 3) << 5;      // 0,32,64,96
                const int e   = eh * 64 + e_l;
                const long vb = obase + ((long)e << 11) + (m_base & 2047) + sq;
#pragma unroll
                for (int j = 0; j < 4; j++)
                    *(bf16x8*)&VT[vb + j * 8] = *(const bf16x8*)&Cs[e_l * 136 + sq + j * 8];
            }
            __syncthreads();
        }
    }
}

// ---------------- causal flash attention ----------------
// Fixed-max softmax: p = exp(s - 12), e^-12 cancels in o/l. Per-lane l accumulates;
// one 4-shuffle reduce per q-tile. XCD-swizzled 1-D grid; paired q-tiles (qt=xb, 31-xb).
__launch_bounds__(256)
__global__ void flash_kernel(const bf16* __restrict__ Q, const bf16* __restrict__ K,
                             const bf16* __restrict__ Vt, bf16* __restrict__ Z) {
    __shared__ __align__(16) bf16 Ks[64 * 136];   // pad 128->136
    __shared__ __align__(16) bf16 Vs[128 * 72];   // pad 64->72, rows = e
    __shared__ __align__(16) bf16 Ps[64 * 72];    // per-wave-private 16-row regions
    const int tid = threadIdx.x, w = tid >> 6, lane = tid & 63;
    const int quad = lane >> 4, l16 = lane & 15;
    const int n = blockIdx.x;
    const int xb = n >> 5;
    const int bh = (((n >> 3) & 3) << 3) | (n & 7);
    const int b = bh >> 4, h = bh & 15;
    const long qk_base = (long)bh << 18;          // bh*2048*128
    const float FM = 12.0f;                       // fixed softmax max

    for (int half = 0; half < 2; half++) {
        const int qt = half ? (31 - xb) : xb;
        const int qbase = qt * 64;

        bf16x8 qf[4];
#pragma unroll
        for (int ks = 0; ks < 4; ks++)
            qf[ks] = *(const bf16x8*)(Q + qk_base + ((long)(qbase + w * 16 + l16) << 7) + ks * 32 + (quad << 3));

        f32x4 o[8] = {};
        float lsum[4] = {0.f, 0.f, 0.f, 0.f};

        for (int kt = 0; kt <= qt; kt++) {
#pragma unroll
            for (int p = 0; p < 4; p++) {   // stage K tile 64x128
                int t = p * 256 + tid;
                int row = t >> 4, col = (t & 15) << 3;
                *(bf16x8*)&Ks[row * 136 + col] = *(const bf16x8*)(K + qk_base + ((long)(kt * 64 + row) << 7) + col);
            }
#pragma unroll
            for (int p = 0; p < 4; p++) {   // stage V^T tile 128x64
                int t = p * 256 + tid;
                int row = t >> 3, col = (t & 7) << 3;
                *(bf16x8*)&Vs[row * 72 + col] = *(const bf16x8*)(Vt + qk_base + ((long)row << 11) + kt * 64 + col);
            }
            __syncthreads();

            f32x4 sc[4] = {};
#pragma unroll
            for (int nt = 0; nt < 4; nt++)
#pragma unroll
                for (int ks = 0; ks < 4; ks++) {
                    bf16x8 kf = *(const bf16x8*)&Ks[(nt * 16 + l16) * 136 + ks * 32 + (quad << 3)];
                    sc[nt] = __builtin_amdgcn_mfma_f32_16x16x32_bf16(qf[ks], kf, sc[nt], 0, 0, 0);
                }

            if (kt == qt) {   // diagonal tile: causal mask (exp underflows to exact 0)
#pragma unroll
                for (int nt = 0; nt < 4; nt++)
#pragma unroll
                    for (int r = 0; r < 4; r++) {
                        int qrow = qbase + w * 16 + quad * 4 + r;
                        int kv = kt * 64 + nt * 16 + l16;
                        if (kv > qrow) sc[nt][r] = -3.0e38f;
                    }
            }

            // p = exp(s - FM); accumulate per-lane row sums; write P to per-wave LDS region
#pragma unroll
            for (int nt = 0; nt < 4; nt++)
#pragma unroll
                for (int r = 0; r < 4; r++) {
                    float p = __expf(sc[nt][r] - FM);
                    lsum[r] += p;
                    Ps[(w * 16 + quad * 4 + r) * 72 + nt * 16 + l16] = (bf16)p;
                }
            // no barrier: Ps region is wave-private; in-wave lgkmcnt orders write->read

#pragma unroll
            for (int kk = 0; kk < 2; kk++) {
                bf16x8 pf = *(const bf16x8*)&Ps[(w * 16 + l16) * 72 + kk * 32 + (quad << 3)];
#pragma unroll
                for (int dt = 0; dt < 8; dt++) {
                    bf16x8 vf = *(const bf16x8*)&Vs[(dt * 16 + l16) * 72 + kk * 32 + (quad << 3)];
                    o[dt] = __builtin_amdgcn_mfma_f32_16x16x32_bf16(pf, vf, o[dt], 0, 0, 0);
                }
            }
            __syncthreads();   // protect Ks/Vs (and Ps) before next staging
        }

        // single end-of-tile reduction of l across the 16-lane row group
#pragma unroll
        for (int r = 0; r < 4; r++) {
            float l = lsum[r];
            l += __shfl_xor(l, 1);
            l += __shfl_xor(l, 2);
            l += __shfl_xor(l, 4);
            l += __shfl_xor(l, 8);
            float inv = 1.f / l;
            int qrow = qbase + w * 16 + quad * 4 + r;
            long zr = ((long)(b * 2048 + qrow) << 11) + h * 128;
#pragma unroll
            for (int dt = 0; dt < 8; dt++)
                Z[zr + dt * 16 + l16] = (bf16)(o[dt][r] * inv);
        }
    }
}

// ---------------- output projection GEMM: fp32 out + bias (round-4 form) ----------------
__launch_bounds__(256)
__global__ void gemm_o_kernel(const bf16* __restrict__ A, const bf16* __restrict__ Bm,
                              const float* __restrict__ bias, float* __restrict__ Of) {
    __shared__ __align__(16) bf16 As[128 * 32];
    __shared__ __align__(16) bf16 Bs[128 * 32];
    const int tid = threadIdx.x;
    const int w = tid >> 6, lane = tid & 63;
    const int quad = lane >> 4, l16 = lane & 15;
    const int wm = w & 1, wn = w >> 1;
    const int m_base = blockIdx.x << 7, n_base = blockIdx.y << 7;

    const int srow = lane >> 2;
    const int scol = (lane & 3) << 3;
    const int ab0 = w * 2, ab1 = w * 2 + 1;
    const bf16* gA0 = A  + (long)(m_base + ab0 * 16 + srow) * 2048 + scol;
    const bf16* gA1 = A  + (long)(m_base + ab1 * 16 + srow) * 2048 + scol;
    const bf16* gB0 = Bm + (long)(n_base + ab0 * 16 + srow) * 2048 + scol;
    const bf16* gB1 = Bm + (long)(n_base + ab1 * 16 + srow) * 2048 + scol;
    bf16* lA0 = &As[ab0 * 512];
    bf16* lA1 = &As[ab1 * 512];
    bf16* lB0 = &Bs[ab0 * 512];
    bf16* lB1 = &Bs[ab1 * 512];

    f32x4 acc[4][4] = {};

    for (int k0 = 0; k0 < 2048; k0 += 32) {
        __builtin_amdgcn_global_load_lds((const __attribute__((address_space(1))) void*)(gA0 + k0),
                                         (__attribute__((address_space(3))) void*)lA0, 16, 0, 0);
        __builtin_amdgcn_global_load_lds((const __attribute__((address_space(1))) void*)(gA1 + k0),
                                         (__attribute__((address_space(3))) void*)lA1, 16, 0, 0);
        __builtin_amdgcn_global_load_lds((const __attribute__((address_space(1))) void*)(gB0 + k0),
                                         (__attribute__((address_space(3))) void*)lB0, 16, 0, 0);
        __builtin_amdgcn_global_load_lds((const __attribute__((address_space(1))) void*)(gB1 + k0),
                                         (__attribute__((address_space(3))) void*)lB1, 16, 0, 0);
        __syncthreads();

        bf16x8 af[4], bfr[4];
#pragma unroll
        for (int mt = 0; mt < 4; mt++)
            af[mt] = *(const bf16x8*)&As[((wm * 64 + mt * 16 + l16) << 5) + (quad << 3)];
#pragma unroll
        for (int nt = 0; nt < 4; nt++)
            bfr[nt] = *(const bf16x8*)&Bs[((wn * 64 + nt * 16 + l16) << 5) + (quad << 3)];
#pragma unroll
        for (int mt = 0; mt < 4; mt++)
#pragma unroll
            for (int nt = 0; nt < 4; nt++)
                acc[mt][nt] = __builtin_amdgcn_mfma_f32_16x16x32_bf16(af[mt], bfr[nt], acc[mt][nt], 0, 0, 0);
        __syncthreads();
    }

#pragma unroll
    for (int nt = 0; nt < 4; nt++) {
        int col = n_base + wn * 64 + nt * 16 + l16;
        float bv = bias[col];
#pragma unroll
        for (int mt = 0; mt < 4; mt++) {
#pragma unroll
            for (int r = 0; r < 4; r++) {
                int row = m_base + wm * 64 + mt * 16 + quad * 4 + r;
                Of[((long)row << 11) + col] = acc[mt][nt][r] + bv;
            }
        }
    }
}

extern "C" void kernel_launch(void* const* d_in, const int* in_sizes, int n_in,
                              void* d_out, int out_size, void* d_ws, size_t ws_size,
                              hipStream_t stream) {
    (void)in_sizes; (void)n_in; (void)out_size; (void)ws_size;
    const float* qin = (const float*)d_in[0];
    const float* kin = (const float*)d_in[1];
    const float* vin = (const float*)d_in[2];
    const float* WQ  = (const float*)d_in[3];
    const float* WK  = (const float*)d_in[4];
    const float* WV  = (const float*)d_in[5];
    const float* WO  = (const float*)d_in[6];
    const float* bQ  = (const float*)d_in[7];
    const float* bK  = (const float*)d_in[8];
    const float* bV  = (const float*)d_in[9];
    const float* bO  = (const float*)d_in[10];
    float* out = (float*)d_out;

    bf16* ws = (bf16*)d_ws;
    bf16* XQ  = ws + 0L;          // 8,388,608 elems each
    bf16* XK  = ws + 8388608L;
    bf16* XV  = ws + 16777216L;
    bf16* WQT = ws + 25165824L;   // 4,194,304 each
    bf16* WKT = ws + 29360128L;
    bf16* WVT = ws + 33554432L;
    bf16* WOT = ws + 37748736L;
    bf16* QB  = ws + 41943040L;   // [bh][s][e]
    bf16* KB  = ws + 50331648L;   // [bh][s][e]
    bf16* VT  = ws + 58720256L;   // [bh][e][s]   total 67,108,864 elems = 128 MiB
    bf16* Z   = XQ;               // reuse: XQ dead after qkv_gemm dispatch completes

    prep_kernel<<<dim3(16384, 5), 256, 0, stream>>>(qin, kin, vin, WQ, WK, WV, WO,
                                                    XQ, XK, XV, WQT, WKT, WVT, WOT);
    qkv_gemm_kernel<<<dim3(32, 16, 3), 256, 0, stream>>>(XQ, XK, XV, WQT, WKT, WVT,
                                                         bQ, bK, bV, QB, KB, VT);
    flash_kernel<<<512, 256, 0, stream>>>(QB, KB, VT, Z);
    gemm_o_kernel<<<dim3(32, 16), 256, 0, stream>>>(Z, WOT, bO, out);
}

// Round 8
// 476.238 us; speedup vs baseline: 1.1800x; 1.1439x over previous
//
#include <hip/hip_runtime.h>
#include <hip/hip_bf16.h>
#include <cmath>

typedef __bf16 bf16;
typedef __bf16 bf16x8 __attribute__((ext_vector_type(8)));
typedef __bf16 bf16x4 __attribute__((ext_vector_type(4)));
typedef float  f32x4  __attribute__((ext_vector_type(4)));

// Problem constants: B=2, S=2048, D=2048, H=16, DH=128, full rotary (128), scale=1/sqrt(128)

// ---------------- merged preprocessing: X fp32->bf16 + all 4 weight transposes ----------------
// grid (16384, 5): y=0 -> convert qin/kin/vin (2 elems/thread each, float2);
// y=1..3 -> W_{QKV}(H,D,DH) -> [h*128+e][d] bf16; y=4 -> W_O(H,DH,D) -> [d][h*128+e] bf16.
__global__ void prep_kernel(const float* __restrict__ qin, const float* __restrict__ kin,
                            const float* __restrict__ vin,
                            const float* __restrict__ WQ, const float* __restrict__ WK,
                            const float* __restrict__ WV, const float* __restrict__ WO,
                            bf16* __restrict__ XQ, bf16* __restrict__ XK, bf16* __restrict__ XV,
                            bf16* __restrict__ WQT, bf16* __restrict__ WKT,
                            bf16* __restrict__ WVT, bf16* __restrict__ WOT) {
    int y = blockIdx.y;
    int o = blockIdx.x * 256 + threadIdx.x;       // 4,194,304 threads per plane
    if (y == 0) {
        int i = o * 2;                            // 8,388,608 elems per tensor
        float2 a = *(const float2*)(qin + i);
        float2 b = *(const float2*)(kin + i);
        float2 c = *(const float2*)(vin + i);
        bf16 ra[2] = { (bf16)a.x, (bf16)a.y };
        bf16 rb[2] = { (bf16)b.x, (bf16)b.y };
        bf16 rc[2] = { (bf16)c.x, (bf16)c.y };
        *(short*)&XQ[i] = *(short*)&ra[0]; *(short*)&XQ[i+1] = *(short*)&ra[1];
        *(short*)&XK[i] = *(short*)&rb[0]; *(short*)&XK[i+1] = *(short*)&rb[1];
        *(short*)&XV[i] = *(short*)&rc[0]; *(short*)&XV[i+1] = *(short*)&rc[1];
    } else if (y < 4) {
        const float* W = (y == 1) ? WQ : (y == 2) ? WK : WV;
        bf16* Wt       = (y == 1) ? WQT : (y == 2) ? WKT : WVT;
        int d = o & 2047;
        int he = o >> 11;
        int e = he & 127, h = he >> 7;
        Wt[o] = (bf16)W[(h << 18) + (d << 7) + e];   // h*2048*128 + d*128 + e
    } else {
        int he = o & 2047;
        int d = o >> 11;
        WOT[o] = (bf16)WO[(he << 11) + d];
    }
}

// ---------------- fused QKV projection GEMM (z selects Q/K/V), BK=32 ----------------
// Round-4 form (131.5 us measured): BK=32, LDS 33.8 KB -> 3 blocks/CU. BK=64 regressed
// (occupancy 31->21%, +15 us) — occupancy dominates barrier amortization here.
// Wave n-tile remap: col = wn*32 + (nt&1)*16 + (nt>>1)*64 + l16 so the rotary partner
// pair (e, e+64) lives in the same lane as acc[mt][nt] / acc[mt][nt+2].
// z=0: rotary+scale -> QB[bh][s][e]; z=1: rotary -> KB; z=2: +bias -> VT[bh][e][s].
__launch_bounds__(256)
__global__ void qkv_gemm_kernel(const bf16* __restrict__ XQ, const bf16* __restrict__ XK,
                                const bf16* __restrict__ XV,
                                const bf16* __restrict__ WQT, const bf16* __restrict__ WKT,
                                const bf16* __restrict__ WVT,
                                const float* __restrict__ bQ, const float* __restrict__ bK,
                                const float* __restrict__ bV,
                                bf16* __restrict__ QB, bf16* __restrict__ KB,
                                bf16* __restrict__ VT) {
    __shared__ __align__(16) bf16 As[128 * 32];
    __shared__ __align__(16) bf16 Bs[128 * 32];
    __shared__ __align__(16) bf16 Cs[64 * 136];   // V-transpose staging (17 KB)
    const int z = blockIdx.z;
    const bf16* A  = (z == 0) ? XQ  : (z == 1) ? XK  : XV;
    const bf16* Bm = (z == 0) ? WQT : (z == 1) ? WKT : WVT;
    const float* bias = (z == 0) ? bQ : (z == 1) ? bK : bV;

    const int tid = threadIdx.x;
    const int w = tid >> 6, lane = tid & 63;
    const int quad = lane >> 4, l16 = lane & 15;
    const int wm = w & 1, wn = w >> 1;
    const int m_base = blockIdx.x << 7, n_base = blockIdx.y << 7;

    const int srow = lane >> 2;           // 0..15
    const int scol = (lane & 3) << 3;     // 0,8,16,24
    const int ab0 = w * 2, ab1 = w * 2 + 1;
    const bf16* gA0 = A  + (long)(m_base + ab0 * 16 + srow) * 2048 + scol;
    const bf16* gA1 = A  + (long)(m_base + ab1 * 16 + srow) * 2048 + scol;
    const bf16* gB0 = Bm + (long)(n_base + ab0 * 16 + srow) * 2048 + scol;
    const bf16* gB1 = Bm + (long)(n_base + ab1 * 16 + srow) * 2048 + scol;
    bf16* lA0 = &As[ab0 * 512];
    bf16* lA1 = &As[ab1 * 512];
    bf16* lB0 = &Bs[ab0 * 512];
    bf16* lB1 = &Bs[ab1 * 512];

    f32x4 acc[4][4] = {};

    for (int k0 = 0; k0 < 2048; k0 += 32) {
        __builtin_amdgcn_global_load_lds((const __attribute__((address_space(1))) void*)(gA0 + k0),
                                         (__attribute__((address_space(3))) void*)lA0, 16, 0, 0);
        __builtin_amdgcn_global_load_lds((const __attribute__((address_space(1))) void*)(gA1 + k0),
                                         (__attribute__((address_space(3))) void*)lA1, 16, 0, 0);
        __builtin_amdgcn_global_load_lds((const __attribute__((address_space(1))) void*)(gB0 + k0),
                                         (__attribute__((address_space(3))) void*)lB0, 16, 0, 0);
        __builtin_amdgcn_global_load_lds((const __attribute__((address_space(1))) void*)(gB1 + k0),
                                         (__attribute__((address_space(3))) void*)lB1, 16, 0, 0);
        __syncthreads();

        bf16x8 af[4], bfr[4];
#pragma unroll
        for (int mt = 0; mt < 4; mt++)
            af[mt] = *(const bf16x8*)&As[((wm * 64 + mt * 16 + l16) << 5) + (quad << 3)];
#pragma unroll
        for (int nt = 0; nt < 4; nt++) {
            int nrow = wn * 32 + (nt & 1) * 16 + (nt >> 1) * 64 + l16;
            bfr[nt] = *(const bf16x8*)&Bs[(nrow << 5) + (quad << 3)];
        }
#pragma unroll
        for (int mt = 0; mt < 4; mt++)
#pragma unroll
            for (int nt = 0; nt < 4; nt++)
                acc[mt][nt] = __builtin_amdgcn_mfma_f32_16x16x32_bf16(af[mt], bfr[nt], acc[mt][nt], 0, 0, 0);
        __syncthreads();
    }

    const int bq = m_base >> 11;          // batch (whole block same batch)
    const int h  = n_base >> 7;           // head  (N-tile == head width)
    const long obase = ((long)(bq * 16 + h)) << 18;

    if (z <= 1) {
        // rotary epilogue, partner pair in-lane: acc[mt][nt] (e_lo) with acc[mt][nt+2] (e_lo+64)
        bf16* O = (z == 0) ? QB : KB;
        const float scl = (z == 0) ? 0.08838834764831845f : 1.0f;   // 1/sqrt(128) folded into Q
#pragma unroll
        for (int nt = 0; nt < 2; nt++) {
            const int e_lo = wn * 32 + nt * 16 + l16;               // 0..63
            const float bv_lo = bias[n_base + e_lo];
            const float bv_hi = bias[n_base + e_lo + 64];
            const float inv_freq = exp2f((float)e_lo * -0.20762050593046f);  // 10000^(-e/64)
#pragma unroll
            for (int mt = 0; mt < 4; mt++) {
#pragma unroll
                for (int r = 0; r < 4; r++) {
                    int s = (m_base & 2047) + wm * 64 + mt * 16 + quad * 4 + r;
                    float sn, cs;
                    __sincosf((float)s * inv_freq, &sn, &cs);
                    float x0 = acc[mt][nt][r]     + bv_lo;
                    float x1 = acc[mt][nt + 2][r] + bv_hi;
                    O[obase + ((long)s << 7) + e_lo]      = (bf16)((x0 * cs - x1 * sn) * scl);
                    O[obase + ((long)s << 7) + e_lo + 64] = (bf16)((x1 * cs + x0 * sn) * scl);
                }
            }
        }
    } else {
        // V: transpose 128x128 tile to VT[bh][e][s] via LDS, two e-halves of 64
#pragma unroll
        for (int eh = 0; eh < 2; eh++) {
#pragma unroll
            for (int nt2 = 0; nt2 < 2; nt2++) {
                const int nt = eh * 2 + nt2;
                const int e_l = wn * 32 + nt2 * 16 + l16;    // 0..63 local within half
                const float bv = bias[n_base + eh * 64 + e_l];
#pragma unroll
                for (int mt = 0; mt < 4; mt++) {
                    int s0 = wm * 64 + mt * 16 + quad * 4;
                    bf16x4 pk = { (bf16)(acc[mt][nt][0] + bv), (bf16)(acc[mt][nt][1] + bv),
                                  (bf16)(acc[mt][nt][2] + bv), (bf16)(acc[mt][nt][3] + bv) };
                    *(bf16x4*)&Cs[e_l * 136 + s0] = pk;
                }
            }
            __syncthreads();
            {
                const int e_l = tid >> 2;            // 0..63
                const int sq  = (tid & 3) << 5;      // 0,32,64,96
                const int e   = eh * 64 + e_l;
                const long vb = obase + ((long)e << 11) + (m_base & 2047) + sq;
#pragma unroll
                for (int j = 0; j < 4; j++)
                    *(bf16x8*)&VT[vb + j * 8] = *(const bf16x8*)&Cs[e_l * 136 + sq + j * 8];
            }
            __syncthreads();
        }
    }
}

// ---------------- causal flash attention ----------------
// 1024 single-q-tile blocks: n&7 -> XCD (same-bh blocks share one L2), qt = 31 - n>>5
// (heavy tiles dispatch first for tail packing). Register-prefetch pipeline: kt+1's
// K/V tiles load into VGPRs during kt's compute. V tile = 128 e-rows x 64 s-cols =
// 4 chunks of (256 thr x 8 elems) — va[4]/vb2[4] (round-7 bug: only 2 chunks staged).
// Fixed-max softmax: p = exp(s - 12), e^-12 cancels in o/l.
// __launch_bounds__(256,3): 3 waves/EU = 3 blocks/CU (LDS-limited anyway), VGPR cap ~168.
__launch_bounds__(256, 3)
__global__ void flash_kernel(const bf16* __restrict__ Q, const bf16* __restrict__ K,
                             const bf16* __restrict__ Vt, bf16* __restrict__ Z) {
    __shared__ __align__(16) bf16 Ks[64 * 136];   // pad 128->136
    __shared__ __align__(16) bf16 Vs[128 * 72];   // pad 64->72, rows = e
    __shared__ __align__(16) bf16 Ps[64 * 72];    // per-wave-private 16-row regions
    const int tid = threadIdx.x, w = tid >> 6, lane = tid & 63;
    const int quad = lane >> 4, l16 = lane & 15;
    const int n = blockIdx.x;
    const int bh = (n & 7) | (((n >> 3) & 3) << 3);   // 0..31, n%8 = bh%8 (XCD-local)
    const int qt = 31 - (n >> 5);                     // heavy first
    const int b = bh >> 4, h = bh & 15;
    const long qk_base = (long)bh << 18;              // bh*2048*128
    const int qbase = qt << 6;
    const float FM = 12.0f;                           // fixed softmax max

    // per-thread staging coordinates
    const int kr_row = tid >> 4;          // 0..15   (K: 4 chunks of 16 rows)
    const int kr_col = (tid & 15) << 3;
    const int vr_row = tid >> 3;          // 0..31   (V^T: 4 chunks of 32 e-rows)
    const int vr_col = (tid & 7) << 3;
    const bf16* Kg = K  + qk_base + (long)kr_row * 128 + kr_col;
    const bf16* Vg = Vt + qk_base + (long)vr_row * 2048 + vr_col;

    bf16x8 qf[4];
#pragma unroll
    for (int ks = 0; ks < 4; ks++)
        qf[ks] = *(const bf16x8*)(Q + qk_base + ((long)(qbase + w * 16 + l16) << 7) + ks * 32 + (quad << 3));

    // prefetch kt=0 into registers
    bf16x8 va[4], ka[4], vb2[4], kb[4];
#pragma unroll
    for (int p = 0; p < 4; p++) va[p] = *(const bf16x8*)(Vg + (long)p * 65536);   // p*32 e-rows
#pragma unroll
    for (int p = 0; p < 4; p++) ka[p] = *(const bf16x8*)(Kg + (long)(p * 16) * 128);

    f32x4 o[8] = {};
    float lsum[4] = {0.f, 0.f, 0.f, 0.f};

    for (int kt = 0; kt <= qt; kt++) {
        // stage current tile to LDS
#pragma unroll
        for (int p = 0; p < 4; p++)
            *(bf16x8*)&Vs[(p * 32 + vr_row) * 72 + vr_col] = va[p];
#pragma unroll
        for (int p = 0; p < 4; p++)
            *(bf16x8*)&Ks[(p * 16 + kr_row) * 136 + kr_col] = ka[p];
        // issue next tile's loads (no wait)
        if (kt < qt) {
            const long koff = (long)(kt + 1) * 64;
#pragma unroll
            for (int p = 0; p < 4; p++) vb2[p] = *(const bf16x8*)(Vg + (long)p * 65536 + koff);
#pragma unroll
            for (int p = 0; p < 4; p++) kb[p] = *(const bf16x8*)(Kg + (koff + p * 16) * 128);
        }
        __syncthreads();

        f32x4 sc[4] = {};
#pragma unroll
        for (int nt = 0; nt < 4; nt++)
#pragma unroll
            for (int ks = 0; ks < 4; ks++) {
                bf16x8 kf = *(const bf16x8*)&Ks[(nt * 16 + l16) * 136 + ks * 32 + (quad << 3)];
                sc[nt] = __builtin_amdgcn_mfma_f32_16x16x32_bf16(qf[ks], kf, sc[nt], 0, 0, 0);
            }

        if (kt == qt) {   // diagonal tile: causal mask (exp underflows to exact 0)
#pragma unroll
            for (int nt = 0; nt < 4; nt++)
#pragma unroll
                for (int r = 0; r < 4; r++) {
                    int qrow = qbase + w * 16 + quad * 4 + r;
                    int kv = (qt << 6) + nt * 16 + l16;
                    if (kv > qrow) sc[nt][r] = -3.0e38f;
                }
        }

        // p = exp(s - FM); accumulate per-lane row sums; write P to per-wave LDS region
#pragma unroll
        for (int nt = 0; nt < 4; nt++)
#pragma unroll
            for (int r = 0; r < 4; r++) {
                float p = __expf(sc[nt][r] - FM);
                lsum[r] += p;
                Ps[(w * 16 + quad * 4 + r) * 72 + nt * 16 + l16] = (bf16)p;
            }
        // no barrier: Ps region is wave-private; in-wave lgkmcnt orders write->read

#pragma unroll
        for (int kk = 0; kk < 2; kk++) {
            bf16x8 pf = *(const bf16x8*)&Ps[(w * 16 + l16) * 72 + kk * 32 + (quad << 3)];
#pragma unroll
            for (int dt = 0; dt < 8; dt++) {
                bf16x8 vf = *(const bf16x8*)&Vs[(dt * 16 + l16) * 72 + kk * 32 + (quad << 3)];
                o[dt] = __builtin_amdgcn_mfma_f32_16x16x32_bf16(pf, vf, o[dt], 0, 0, 0);
            }
        }
        __syncthreads();   // protect Ks/Vs before next iteration's staging writes

        // rotate prefetched registers
#pragma unroll
        for (int p = 0; p < 4; p++) va[p] = vb2[p];
#pragma unroll
        for (int p = 0; p < 4; p++) ka[p] = kb[p];
    }

    // single end-of-tile reduction of l across the 16-lane row group
#pragma unroll
    for (int r = 0; r < 4; r++) {
        float l = lsum[r];
        l += __shfl_xor(l, 1);
        l += __shfl_xor(l, 2);
        l += __shfl_xor(l, 4);
        l += __shfl_xor(l, 8);
        float inv = 1.f / l;
        int qrow = qbase + w * 16 + quad * 4 + r;
        long zr = ((long)(b * 2048 + qrow) << 11) + h * 128;
#pragma unroll
        for (int dt = 0; dt < 8; dt++)
            Z[zr + dt * 16 + l16] = (bf16)(o[dt][r] * inv);
    }
}

// ---------------- output projection GEMM: fp32 out + bias ----------------
__launch_bounds__(256)
__global__ void gemm_o_kernel(const bf16* __restrict__ A, const bf16* __restrict__ Bm,
                              const float* __restrict__ bias, float* __restrict__ Of) {
    __shared__ __align__(16) bf16 As[128 * 32];
    __shared__ __align__(16) bf16 Bs[128 * 32];
    const int tid = threadIdx.x;
    const int w = tid >> 6, lane = tid & 63;
    const int quad = lane >> 4, l16 = lane & 15;
    const int wm = w & 1, wn = w >> 1;
    const int m_base = blockIdx.x << 7, n_base = blockIdx.y << 7;

    const int srow = lane >> 2;
    const int scol = (lane & 3) << 3;
    const int ab0 = w * 2, ab1 = w * 2 + 1;
    const bf16* gA0 = A  + (long)(m_base + ab0 * 16 + srow) * 2048 + scol;
    const bf16* gA1 = A  + (long)(m_base + ab1 * 16 + srow) * 2048 + scol;
    const bf16* gB0 = Bm + (long)(n_base + ab0 * 16 + srow) * 2048 + scol;
    const bf16* gB1 = Bm + (long)(n_base + ab1 * 16 + srow) * 2048 + scol;
    bf16* lA0 = &As[ab0 * 512];
    bf16* lA1 = &As[ab1 * 512];
    bf16* lB0 = &Bs[ab0 * 512];
    bf16* lB1 = &Bs[ab1 * 512];

    f32x4 acc[4][4] = {};

    for (int k0 = 0; k0 < 2048; k0 += 32) {
        __builtin_amdgcn_global_load_lds((const __attribute__((address_space(1))) void*)(gA0 + k0),
                                         (__attribute__((address_space(3))) void*)lA0, 16, 0, 0);
        __builtin_amdgcn_global_load_lds((const __attribute__((address_space(1))) void*)(gA1 + k0),
                                         (__attribute__((address_space(3))) void*)lA1, 16, 0, 0);
        __builtin_amdgcn_global_load_lds((const __attribute__((address_space(1))) void*)(gB0 + k0),
                                         (__attribute__((address_space(3))) void*)lB0, 16, 0, 0);
        __builtin_amdgcn_global_load_lds((const __attribute__((address_space(1))) void*)(gB1 + k0),
                                         (__attribute__((address_space(3))) void*)lB1, 16, 0, 0);
        __syncthreads();

        bf16x8 af[4], bfr[4];
#pragma unroll
        for (int mt = 0; mt < 4; mt++)
            af[mt] = *(const bf16x8*)&As[((wm * 64 + mt * 16 + l16) << 5) + (quad << 3)];
#pragma unroll
        for (int nt = 0; nt < 4; nt++)
            bfr[nt] = *(const bf16x8*)&Bs[((wn * 64 + nt * 16 + l16) << 5) + (quad << 3)];
#pragma unroll
        for (int mt = 0; mt < 4; mt++)
#pragma unroll
            for (int nt = 0; nt < 4; nt++)
                acc[mt][nt] = __builtin_amdgcn_mfma_f32_16x16x32_bf16(af[mt], bfr[nt], acc[mt][nt], 0, 0, 0);
        __syncthreads();
    }

#pragma unroll
    for (int nt = 0; nt < 4; nt++) {
        int col = n_base + wn * 64 + nt * 16 + l16;
        float bv = bias[col];
#pragma unroll
        for (int mt = 0; mt < 4; mt++) {
#pragma unroll
            for (int r = 0; r < 4; r++) {
                int row = m_base + wm * 64 + mt * 16 + quad * 4 + r;
                Of[((long)row << 11) + col] = acc[mt][nt][r] + bv;
            }
        }
    }
}

extern "C" void kernel_launch(void* const* d_in, const int* in_sizes, int n_in,
                              void* d_out, int out_size, void* d_ws, size_t ws_size,
                              hipStream_t stream) {
    (void)in_sizes; (void)n_in; (void)out_size; (void)ws_size;
    const float* qin = (const float*)d_in[0];
    const float* kin = (const float*)d_in[1];
    const float* vin = (const float*)d_in[2];
    const float* WQ  = (const float*)d_in[3];
    const float* WK  = (const float*)d_in[4];
    const float* WV  = (const float*)d_in[5];
    const float* WO  = (const float*)d_in[6];
    const float* bQ  = (const float*)d_in[7];
    const float* bK  = (const float*)d_in[8];
    const float* bV  = (const float*)d_in[9];
    const float* bO  = (const float*)d_in[10];
    float* out = (float*)d_out;

    bf16* ws = (bf16*)d_ws;
    bf16* XQ  = ws + 0L;          // 8,388,608 elems each
    bf16* XK  = ws + 8388608L;
    bf16* XV  = ws + 16777216L;
    bf16* WQT = ws + 25165824L;   // 4,194,304 each
    bf16* WKT = ws + 29360128L;
    bf16* WVT = ws + 33554432L;
    bf16* WOT = ws + 37748736L;
    bf16* QB  = ws + 41943040L;   // [bh][s][e]
    bf16* KB  = ws + 50331648L;   // [bh][s][e]
    bf16* VT  = ws + 58720256L;   // [bh][e][s]   total 67,108,864 elems = 128 MiB
    bf16* Z   = XQ;               // reuse: XQ dead after qkv_gemm dispatch completes

    prep_kernel<<<dim3(16384, 5), 256, 0, stream>>>(qin, kin, vin, WQ, WK, WV, WO,
                                                    XQ, XK, XV, WQT, WKT, WVT, WOT);
    qkv_gemm_kernel<<<dim3(32, 16, 3), 256, 0, stream>>>(XQ, XK, XV, WQT, WKT, WVT,
                                                         bQ, bK, bV, QB, KB, VT);
    flash_kernel<<<1024, 256, 0, stream>>>(QB, KB, VT, Z);
    gemm_o_kernel<<<dim3(32, 16), 256, 0, stream>>>(Z, WOT, bO, out);
}

// Round 9
// 427.252 us; speedup vs baseline: 1.3153x; 1.1147x over previous
//
#include <hip/hip_runtime.h>
#include <hip/hip_bf16.h>
#include <cmath>

typedef __bf16 bf16;
typedef __bf16 bf16x8 __attribute__((ext_vector_type(8)));
typedef __bf16 bf16x4 __attribute__((ext_vector_type(4)));
typedef float  f32x4  __attribute__((ext_vector_type(4)));

// Problem constants: B=2, S=2048, D=2048, H=16, DH=128, full rotary (128), scale=1/sqrt(128)

// ---------------- fp32 -> bf16 convert (3 tensors at once, float4) ----------------
__global__ void xcvt_kernel(const float* __restrict__ a, const float* __restrict__ b,
                            const float* __restrict__ c,
                            bf16* __restrict__ oa, bf16* __restrict__ ob, bf16* __restrict__ oc) {
    int i = (blockIdx.x * 256 + threadIdx.x) * 4;   // 8192 blocks * 256 * 4 = 8388608
    float4 va = *(const float4*)(a + i);
    float4 vb = *(const float4*)(b + i);
    float4 vc = *(const float4*)(c + i);
    bf16x4 ra = { (bf16)va.x, (bf16)va.y, (bf16)va.z, (bf16)va.w };
    bf16x4 rb = { (bf16)vb.x, (bf16)vb.y, (bf16)vb.z, (bf16)vb.w };
    bf16x4 rc = { (bf16)vc.x, (bf16)vc.y, (bf16)vc.z, (bf16)vc.w };
    *(bf16x4*)(oa + i) = ra;
    *(bf16x4*)(ob + i) = rb;
    *(bf16x4*)(oc + i) = rc;
}

// ---------------- LDS-tiled weight transposes (coalesced read AND write) ----------------
// grid (1024, 4). z<3: per-head transpose W_{QKV}[h](2048d x 128e) -> Wt[h*128+e][d].
// z==3: W_O (2048he x 2048d) -> WoT[d][he]. 64x64 fp32 tiles, pad 65 (2-way banks, free).
__global__ void wtr_kernel(const float* __restrict__ WQ, const float* __restrict__ WK,
                           const float* __restrict__ WV, const float* __restrict__ WO,
                           bf16* __restrict__ WQT, bf16* __restrict__ WKT,
                           bf16* __restrict__ WVT, bf16* __restrict__ WOT) {
    __shared__ float T[64 * 65];
    const int z = blockIdx.y;
    const int bx = blockIdx.x;
    const int tid = threadIdx.x;
    const int tr = tid >> 4;            // 0..15
    const int tc = (tid & 15) * 4;      // 0,4,...,60

    const float* src; bf16* dst;
    long sbase, dbase; int sRS;         // src base/row-stride, dst base
    if (z < 3) {
        src = (z == 0) ? WQ : (z == 1) ? WK : WV;
        dst = (z == 0) ? WQT : (z == 1) ? WKT : WVT;
        int h = bx >> 6, rem = bx & 63;
        int d0 = (rem >> 1) << 6, e0 = (rem & 1) << 6;
        sbase = (long)h * 262144 + (long)d0 * 128 + e0;   // row = d, col = e
        sRS = 128;
        dbase = (long)(h * 128 + e0) * 2048 + d0;         // row = e, col = d
    } else {
        src = WO; dst = WOT;
        int a0 = (bx >> 5) << 6, b0 = (bx & 31) << 6;     // row = he, col = d
        sbase = (long)a0 * 2048 + b0;
        sRS = 2048;
        dbase = (long)b0 * 2048 + a0;                     // row = d, col = he
    }

#pragma unroll
    for (int p = 0; p < 4; p++) {
        int r = p * 16 + tr;
        float4 v = *(const float4*)(src + sbase + (long)r * sRS + tc);
        T[r * 65 + tc]     = v.x;
        T[r * 65 + tc + 1] = v.y;
        T[r * 65 + tc + 2] = v.z;
        T[r * 65 + tc + 3] = v.w;
    }
    __syncthreads();
#pragma unroll
    for (int p = 0; p < 4; p++) {
        int rr = p * 16 + tr;            // dst row within tile
        bf16x4 o = { (bf16)T[tc * 65 + rr],       (bf16)T[(tc + 1) * 65 + rr],
                     (bf16)T[(tc + 2) * 65 + rr], (bf16)T[(tc + 3) * 65 + rr] };
        *(bf16x4*)(dst + dbase + (long)rr * 2048 + tc) = o;
    }
}

// ---------------- fused QKV projection GEMM (z selects Q/K/V), register-prefetch ----------------
// Staging via per-thread bf16x8 loads + 1-iteration prefetch: plain loads carry NO
// visibility obligation at __syncthreads (unlike global_load_lds, which is an LDS write
// through vmcnt and forces a full drain at every barrier — the m97 ~20% stall). Next
// tile's loads issue before the barrier and land during current tile's MFMA.
// LDS pad 32->40 elems: write banks (20*row)%32, period 8 over 16 rows -> 2-way (free).
// Wave n-tile remap: col = wn*32 + (nt&1)*16 + (nt>>1)*64 + l16 so the rotary partner
// pair (e, e+64) lives in the same lane as acc[mt][nt] / acc[mt][nt+2].
// z=0: rotary+scale -> QB[bh][s][e]; z=1: rotary -> KB; z=2: +bias -> VT[bh][e][s].
__launch_bounds__(256, 3)
__global__ void qkv_gemm_kernel(const bf16* __restrict__ XQ, const bf16* __restrict__ XK,
                                const bf16* __restrict__ XV,
                                const bf16* __restrict__ WQT, const bf16* __restrict__ WKT,
                                const bf16* __restrict__ WVT,
                                const float* __restrict__ bQ, const float* __restrict__ bK,
                                const float* __restrict__ bV,
                                bf16* __restrict__ QB, bf16* __restrict__ KB,
                                bf16* __restrict__ VT) {
    __shared__ __align__(16) bf16 As[128 * 40];   // 10.24 KB, pad 40
    __shared__ __align__(16) bf16 Bs[128 * 40];
    __shared__ __align__(16) bf16 Cs[64 * 136];   // V-transpose staging (17 KB)
    const int z = blockIdx.z;
    const bf16* A  = (z == 0) ? XQ  : (z == 1) ? XK  : XV;
    const bf16* Bm = (z == 0) ? WQT : (z == 1) ? WKT : WVT;
    const float* bias = (z == 0) ? bQ : (z == 1) ? bK : bV;

    const int tid = threadIdx.x;
    const int w = tid >> 6, lane = tid & 63;
    const int quad = lane >> 4, l16 = lane & 15;
    const int wm = w & 1, wn = w >> 1;
    const int m_base = blockIdx.x << 7, n_base = blockIdx.y << 7;

    // staging coords: rows srow, srow+64; cols scol..scol+7 (k within tile)
    const int srow = tid >> 2;            // 0..63
    const int scol = (tid & 3) << 3;      // 0,8,16,24
    const bf16* gA = A  + (long)(m_base + srow) * 2048 + scol;
    const bf16* gB = Bm + (long)(n_base + srow) * 2048 + scol;

    f32x4 acc[4][4] = {};
    bf16x8 ar[2], br[2], arn[2], brn[2];
#pragma unroll
    for (int p = 0; p < 2; p++) {
        ar[p] = *(const bf16x8*)(gA + (long)p * 64 * 2048);
        br[p] = *(const bf16x8*)(gB + (long)p * 64 * 2048);
    }

    for (int k0 = 0; k0 < 2048; k0 += 32) {
        // stage current tile (waits only on ar/br — issued a full iteration ago)
#pragma unroll
        for (int p = 0; p < 2; p++) {
            *(bf16x8*)&As[(p * 64 + srow) * 40 + scol] = ar[p];
            *(bf16x8*)&Bs[(p * 64 + srow) * 40 + scol] = br[p];
        }
        // prefetch next tile (no wait; survives the barrier in flight)
        if (k0 + 32 < 2048) {
#pragma unroll
            for (int p = 0; p < 2; p++) {
                arn[p] = *(const bf16x8*)(gA + (long)p * 64 * 2048 + k0 + 32);
                brn[p] = *(const bf16x8*)(gB + (long)p * 64 * 2048 + k0 + 32);
            }
        }
        __syncthreads();

        bf16x8 af[4], bfr[4];
#pragma unroll
        for (int mt = 0; mt < 4; mt++)
            af[mt] = *(const bf16x8*)&As[(wm * 64 + mt * 16 + l16) * 40 + (quad << 3)];
#pragma unroll
        for (int nt = 0; nt < 4; nt++) {
            int nrow = wn * 32 + (nt & 1) * 16 + (nt >> 1) * 64 + l16;
            bfr[nt] = *(const bf16x8*)&Bs[nrow * 40 + (quad << 3)];
        }
#pragma unroll
        for (int mt = 0; mt < 4; mt++)
#pragma unroll
            for (int nt = 0; nt < 4; nt++)
                acc[mt][nt] = __builtin_amdgcn_mfma_f32_16x16x32_bf16(af[mt], bfr[nt], acc[mt][nt], 0, 0, 0);
        __syncthreads();

#pragma unroll
        for (int p = 0; p < 2; p++) { ar[p] = arn[p]; br[p] = brn[p]; }
    }

    const int bq = m_base >> 11;          // batch (whole block same batch)
    const int h  = n_base >> 7;           // head  (N-tile == head width)
    const long obase = ((long)(bq * 16 + h)) << 18;

    if (z <= 1) {
        // rotary epilogue, partner pair in-lane: acc[mt][nt] (e_lo) with acc[mt][nt+2] (e_lo+64)
        bf16* O = (z == 0) ? QB : KB;
        const float scl = (z == 0) ? 0.08838834764831845f : 1.0f;   // 1/sqrt(128) folded into Q
#pragma unroll
        for (int nt = 0; nt < 2; nt++) {
            const int e_lo = wn * 32 + nt * 16 + l16;               // 0..63
            const float bv_lo = bias[n_base + e_lo];
            const float bv_hi = bias[n_base + e_lo + 64];
            const float inv_freq = exp2f((float)e_lo * -0.20762050593046f);  // 10000^(-e/64)
#pragma unroll
            for (int mt = 0; mt < 4; mt++) {
#pragma unroll
                for (int r = 0; r < 4; r++) {
                    int s = (m_base & 2047) + wm * 64 + mt * 16 + quad * 4 + r;
                    float sn, cs;
                    __sincosf((float)s * inv_freq, &sn, &cs);
                    float x0 = acc[mt][nt][r]     + bv_lo;
                    float x1 = acc[mt][nt + 2][r] + bv_hi;
                    O[obase + ((long)s << 7) + e_lo]      = (bf16)((x0 * cs - x1 * sn) * scl);
                    O[obase + ((long)s << 7) + e_lo + 64] = (bf16)((x1 * cs + x0 * sn) * scl);
                }
            }
        }
    } else {
        // V: transpose 128x128 tile to VT[bh][e][s] via LDS, two e-halves of 64
#pragma unroll
        for (int eh = 0; eh < 2; eh++) {
#pragma unroll
            for (int nt2 = 0; nt2 < 2; nt2++) {
                const int nt = eh * 2 + nt2;
                const int e_l = wn * 32 + nt2 * 16 + l16;    // 0..63 local within half
                const float bv = bias[n_base + eh * 64 + e_l];
#pragma unroll
                for (int mt = 0; mt < 4; mt++) {
                    int s0 = wm * 64 + mt * 16 + quad * 4;
                    bf16x4 pk = { (bf16)(acc[mt][nt][0] + bv), (bf16)(acc[mt][nt][1] + bv),
                                  (bf16)(acc[mt][nt][2] + bv), (bf16)(acc[mt][nt][3] + bv) };
                    *(bf16x4*)&Cs[e_l * 136 + s0] = pk;
                }
            }
            __syncthreads();
            {
                const int e_l = tid >> 2;            // 0..63
                const int sq  = (tid & 3) << 5;      // 0,32,64,96
                const int e   = eh * 64 + e_l;
                const long vb = obase + ((long)e << 11) + (m_base & 2047) + sq;
#pragma unroll
                for (int j = 0; j < 4; j++)
                    *(bf16x8*)&VT[vb + j * 8] = *(const bf16x8*)&Cs[e_l * 136 + sq + j * 8];
            }
            __syncthreads();
        }
    }
}

// ---------------- causal flash attention (round-8 form, verified) ----------------
// 1024 single-q-tile blocks: n&7 -> XCD, qt = 31 - n>>5 (heavy first). Register-prefetch
// of kt+1's K/V (4+4 bf16x8). Fixed-max softmax: p = exp(s - 12), cancels in o/l.
__launch_bounds__(256, 3)
__global__ void flash_kernel(const bf16* __restrict__ Q, const bf16* __restrict__ K,
                             const bf16* __restrict__ Vt, bf16* __restrict__ Z) {
    __shared__ __align__(16) bf16 Ks[64 * 136];   // pad 128->136
    __shared__ __align__(16) bf16 Vs[128 * 72];   // pad 64->72, rows = e
    __shared__ __align__(16) bf16 Ps[64 * 72];    // per-wave-private 16-row regions
    const int tid = threadIdx.x, w = tid >> 6, lane = tid & 63;
    const int quad = lane >> 4, l16 = lane & 15;
    const int n = blockIdx.x;
    const int bh = (n & 7) | (((n >> 3) & 3) << 3);   // 0..31, n%8 = bh%8 (XCD-local)
    const int qt = 31 - (n >> 5);                     // heavy first
    const int b = bh >> 4, h = bh & 15;
    const long qk_base = (long)bh << 18;              // bh*2048*128
    const int qbase = qt << 6;
    const float FM = 12.0f;                           // fixed softmax max

    const int kr_row = tid >> 4;          // 0..15   (K: 4 chunks of 16 rows)
    const int kr_col = (tid & 15) << 3;
    const int vr_row = tid >> 3;          // 0..31   (V^T: 4 chunks of 32 e-rows)
    const int vr_col = (tid & 7) << 3;
    const bf16* Kg = K  + qk_base + (long)kr_row * 128 + kr_col;
    const bf16* Vg = Vt + qk_base + (long)vr_row * 2048 + vr_col;

    bf16x8 qf[4];
#pragma unroll
    for (int ks = 0; ks < 4; ks++)
        qf[ks] = *(const bf16x8*)(Q + qk_base + ((long)(qbase + w * 16 + l16) << 7) + ks * 32 + (quad << 3));

    bf16x8 va[4], ka[4], vb2[4], kb[4];
#pragma unroll
    for (int p = 0; p < 4; p++) va[p] = *(const bf16x8*)(Vg + (long)p * 65536);   // p*32 e-rows
#pragma unroll
    for (int p = 0; p < 4; p++) ka[p] = *(const bf16x8*)(Kg + (long)(p * 16) * 128);

    f32x4 o[8] = {};
    float lsum[4] = {0.f, 0.f, 0.f, 0.f};

    for (int kt = 0; kt <= qt; kt++) {
#pragma unroll
        for (int p = 0; p < 4; p++)
            *(bf16x8*)&Vs[(p * 32 + vr_row) * 72 + vr_col] = va[p];
#pragma unroll
        for (int p = 0; p < 4; p++)
            *(bf16x8*)&Ks[(p * 16 + kr_row) * 136 + kr_col] = ka[p];
        if (kt < qt) {
            const long koff = (long)(kt + 1) * 64;
#pragma unroll
            for (int p = 0; p < 4; p++) vb2[p] = *(const bf16x8*)(Vg + (long)p * 65536 + koff);
#pragma unroll
            for (int p = 0; p < 4; p++) kb[p] = *(const bf16x8*)(Kg + (koff + p * 16) * 128);
        }
        __syncthreads();

        f32x4 sc[4] = {};
#pragma unroll
        for (int nt = 0; nt < 4; nt++)
#pragma unroll
            for (int ks = 0; ks < 4; ks++) {
                bf16x8 kf = *(const bf16x8*)&Ks[(nt * 16 + l16) * 136 + ks * 32 + (quad << 3)];
                sc[nt] = __builtin_amdgcn_mfma_f32_16x16x32_bf16(qf[ks], kf, sc[nt], 0, 0, 0);
            }

        if (kt == qt) {   // diagonal tile: causal mask (exp underflows to exact 0)
#pragma unroll
            for (int nt = 0; nt < 4; nt++)
#pragma unroll
                for (int r = 0; r < 4; r++) {
                    int qrow = qbase + w * 16 + quad * 4 + r;
                    int kv = (qt << 6) + nt * 16 + l16;
                    if (kv > qrow) sc[nt][r] = -3.0e38f;
                }
        }

#pragma unroll
        for (int nt = 0; nt < 4; nt++)
#pragma unroll
            for (int r = 0; r < 4; r++) {
                float p = __expf(sc[nt][r] - FM);
                lsum[r] += p;
                Ps[(w * 16 + quad * 4 + r) * 72 + nt * 16 + l16] = (bf16)p;
            }
        // no barrier: Ps region is wave-private; in-wave lgkmcnt orders write->read

#pragma unroll
        for (int kk = 0; kk < 2; kk++) {
            bf16x8 pf = *(const bf16x8*)&Ps[(w * 16 + l16) * 72 + kk * 32 + (quad << 3)];
#pragma unroll
            for (int dt = 0; dt < 8; dt++) {
                bf16x8 vf = *(const bf16x8*)&Vs[(dt * 16 + l16) * 72 + kk * 32 + (quad << 3)];
                o[dt] = __builtin_amdgcn_mfma_f32_16x16x32_bf16(pf, vf, o[dt], 0, 0, 0);
            }
        }
        __syncthreads();   // protect Ks/Vs before next iteration's staging writes

#pragma unroll
        for (int p = 0; p < 4; p++) va[p] = vb2[p];
#pragma unroll
        for (int p = 0; p < 4; p++) ka[p] = kb[p];
    }

#pragma unroll
    for (int r = 0; r < 4; r++) {
        float l = lsum[r];
        l += __shfl_xor(l, 1);
        l += __shfl_xor(l, 2);
        l += __shfl_xor(l, 4);
        l += __shfl_xor(l, 8);
        float inv = 1.f / l;
        int qrow = qbase + w * 16 + quad * 4 + r;
        long zr = ((long)(b * 2048 + qrow) << 11) + h * 128;
#pragma unroll
        for (int dt = 0; dt < 8; dt++)
            Z[zr + dt * 16 + l16] = (bf16)(o[dt][r] * inv);
    }
}

// ---------------- output projection GEMM: register-prefetch, fp32 out + bias ----------------
__launch_bounds__(256, 3)
__global__ void gemm_o_kernel(const bf16* __restrict__ A, const bf16* __restrict__ Bm,
                              const float* __restrict__ bias, float* __restrict__ Of) {
    __shared__ __align__(16) bf16 As[128 * 40];
    __shared__ __align__(16) bf16 Bs[128 * 40];
    const int tid = threadIdx.x;
    const int w = tid >> 6, lane = tid & 63;
    const int quad = lane >> 4, l16 = lane & 15;
    const int wm = w & 1, wn = w >> 1;
    const int m_base = blockIdx.x << 7, n_base = blockIdx.y << 7;

    const int srow = tid >> 2;
    const int scol = (tid & 3) << 3;
    const bf16* gA = A  + (long)(m_base + srow) * 2048 + scol;
    const bf16* gB = Bm + (long)(n_base + srow) * 2048 + scol;

    f32x4 acc[4][4] = {};
    bf16x8 ar[2], br[2], arn[2], brn[2];
#pragma unroll
    for (int p = 0; p < 2; p++) {
        ar[p] = *(const bf16x8*)(gA + (long)p * 64 * 2048);
        br[p] = *(const bf16x8*)(gB + (long)p * 64 * 2048);
    }

    for (int k0 = 0; k0 < 2048; k0 += 32) {
#pragma unroll
        for (int p = 0; p < 2; p++) {
            *(bf16x8*)&As[(p * 64 + srow) * 40 + scol] = ar[p];
            *(bf16x8*)&Bs[(p * 64 + srow) * 40 + scol] = br[p];
        }
        if (k0 + 32 < 2048) {
#pragma unroll
            for (int p = 0; p < 2; p++) {
                arn[p] = *(const bf16x8*)(gA + (long)p * 64 * 2048 + k0 + 32);
                brn[p] = *(const bf16x8*)(gB + (long)p * 64 * 2048 + k0 + 32);
            }
        }
        __syncthreads();

        bf16x8 af[4], bfr[4];
#pragma unroll
        for (int mt = 0; mt < 4; mt++)
            af[mt] = *(const bf16x8*)&As[(wm * 64 + mt * 16 + l16) * 40 + (quad << 3)];
#pragma unroll
        for (int nt = 0; nt < 4; nt++)
            bfr[nt] = *(const bf16x8*)&Bs[(wn * 64 + nt * 16 + l16) * 40 + (quad << 3)];
#pragma unroll
        for (int mt = 0; mt < 4; mt++)
#pragma unroll
            for (int nt = 0; nt < 4; nt++)
                acc[mt][nt] = __builtin_amdgcn_mfma_f32_16x16x32_bf16(af[mt], bfr[nt], acc[mt][nt], 0, 0, 0);
        __syncthreads();

#pragma unroll
        for (int p = 0; p < 2; p++) { ar[p] = arn[p]; br[p] = brn[p]; }
    }

#pragma unroll
    for (int nt = 0; nt < 4; nt++) {
        int col = n_base + wn * 64 + nt * 16 + l16;
        float bv = bias[col];
#pragma unroll
        for (int mt = 0; mt < 4; mt++) {
#pragma unroll
            for (int r = 0; r < 4; r++) {
                int row = m_base + wm * 64 + mt * 16 + quad * 4 + r;
                Of[((long)row << 11) + col] = acc[mt][nt][r] + bv;
            }
        }
    }
}

extern "C" void kernel_launch(void* const* d_in, const int* in_sizes, int n_in,
                              void* d_out, int out_size, void* d_ws, size_t ws_size,
                              hipStream_t stream) {
    (void)in_sizes; (void)n_in; (void)out_size; (void)ws_size;
    const float* qin = (const float*)d_in[0];
    const float* kin = (const float*)d_in[1];
    const float* vin = (const float*)d_in[2];
    const float* WQ  = (const float*)d_in[3];
    const float* WK  = (const float*)d_in[4];
    const float* WV  = (const float*)d_in[5];
    const float* WO  = (const float*)d_in[6];
    const float* bQ  = (const float*)d_in[7];
    const float* bK  = (const float*)d_in[8];
    const float* bV  = (const float*)d_in[9];
    const float* bO  = (const float*)d_in[10];
    float* out = (float*)d_out;

    bf16* ws = (bf16*)d_ws;
    bf16* XQ  = ws + 0L;          // 8,388,608 elems each
    bf16* XK  = ws + 8388608L;
    bf16* XV  = ws + 16777216L;
    bf16* WQT = ws + 25165824L;   // 4,194,304 each
    bf16* WKT = ws + 29360128L;
    bf16* WVT = ws + 33554432L;
    bf16* WOT = ws + 37748736L;
    bf16* QB  = ws + 41943040L;   // [bh][s][e]
    bf16* KB  = ws + 50331648L;   // [bh][s][e]
    bf16* VT  = ws + 58720256L;   // [bh][e][s]   total 67,108,864 elems = 128 MiB
    bf16* Z   = XQ;               // reuse: XQ dead after qkv_gemm dispatch completes

    xcvt_kernel<<<8192, 256, 0, stream>>>(qin, kin, vin, XQ, XK, XV);
    wtr_kernel<<<dim3(1024, 4), 256, 0, stream>>>(WQ, WK, WV, WO, WQT, WKT, WVT, WOT);
    qkv_gemm_kernel<<<dim3(32, 16, 3), 256, 0, stream>>>(XQ, XK, XV, WQT, WKT, WVT,
                                                         bQ, bK, bV, QB, KB, VT);
    flash_kernel<<<1024, 256, 0, stream>>>(QB, KB, VT, Z);
    gemm_o_kernel<<<dim3(32, 16), 256, 0, stream>>>(Z, WOT, bO, out);
}

// Round 10
// 426.323 us; speedup vs baseline: 1.3182x; 1.0022x over previous
//
#include <hip/hip_runtime.h>
#include <hip/hip_bf16.h>
#include <cmath>

typedef __bf16 bf16;
typedef __bf16 bf16x8 __attribute__((ext_vector_type(8)));
typedef __bf16 bf16x4 __attribute__((ext_vector_type(4)));
typedef float  f32x4  __attribute__((ext_vector_type(4)));

// Problem constants: B=2, S=2048, D=2048, H=16, DH=128, full rotary (128), scale=1/sqrt(128)

// ---------------- fp32 -> bf16 convert (3 tensors at once, float4) ----------------
__global__ void xcvt_kernel(const float* __restrict__ a, const float* __restrict__ b,
                            const float* __restrict__ c,
                            bf16* __restrict__ oa, bf16* __restrict__ ob, bf16* __restrict__ oc) {
    int i = (blockIdx.x * 256 + threadIdx.x) * 4;   // 8192 blocks * 256 * 4 = 8388608
    float4 va = *(const float4*)(a + i);
    float4 vb = *(const float4*)(b + i);
    float4 vc = *(const float4*)(c + i);
    bf16x4 ra = { (bf16)va.x, (bf16)va.y, (bf16)va.z, (bf16)va.w };
    bf16x4 rb = { (bf16)vb.x, (bf16)vb.y, (bf16)vb.z, (bf16)vb.w };
    bf16x4 rc = { (bf16)vc.x, (bf16)vc.y, (bf16)vc.z, (bf16)vc.w };
    *(bf16x4*)(oa + i) = ra;
    *(bf16x4*)(ob + i) = rb;
    *(bf16x4*)(oc + i) = rc;
}

// ---------------- LDS-tiled weight transposes (coalesced read AND write) ----------------
// grid (1024, 4). z<3: per-head transpose W_{QKV}[h](2048d x 128e) -> Wt[h*128+e][d].
// z==3: W_O (2048he x 2048d) -> WoT[d][he]. 64x64 fp32 tiles, pad 65 (2-way banks, free).
__global__ void wtr_kernel(const float* __restrict__ WQ, const float* __restrict__ WK,
                           const float* __restrict__ WV, const float* __restrict__ WO,
                           bf16* __restrict__ WQT, bf16* __restrict__ WKT,
                           bf16* __restrict__ WVT, bf16* __restrict__ WOT) {
    __shared__ float T[64 * 65];
    const int z = blockIdx.y;
    const int bx = blockIdx.x;
    const int tid = threadIdx.x;
    const int tr = tid >> 4;            // 0..15
    const int tc = (tid & 15) * 4;      // 0,4,...,60

    const float* src; bf16* dst;
    long sbase, dbase; int sRS;         // src base/row-stride, dst base
    if (z < 3) {
        src = (z == 0) ? WQ : (z == 1) ? WK : WV;
        dst = (z == 0) ? WQT : (z == 1) ? WKT : WVT;
        int h = bx >> 6, rem = bx & 63;
        int d0 = (rem >> 1) << 6, e0 = (rem & 1) << 6;
        sbase = (long)h * 262144 + (long)d0 * 128 + e0;   // row = d, col = e
        sRS = 128;
        dbase = (long)(h * 128 + e0) * 2048 + d0;         // row = e, col = d
    } else {
        src = WO; dst = WOT;
        int a0 = (bx >> 5) << 6, b0 = (bx & 31) << 6;     // row = he, col = d
        sbase = (long)a0 * 2048 + b0;
        sRS = 2048;
        dbase = (long)b0 * 2048 + a0;                     // row = d, col = he
    }

#pragma unroll
    for (int p = 0; p < 4; p++) {
        int r = p * 16 + tr;
        float4 v = *(const float4*)(src + sbase + (long)r * sRS + tc);
        T[r * 65 + tc]     = v.x;
        T[r * 65 + tc + 1] = v.y;
        T[r * 65 + tc + 2] = v.z;
        T[r * 65 + tc + 3] = v.w;
    }
    __syncthreads();
#pragma unroll
    for (int p = 0; p < 4; p++) {
        int rr = p * 16 + tr;            // dst row within tile
        bf16x4 o = { (bf16)T[tc * 65 + rr],       (bf16)T[(tc + 1) * 65 + rr],
                     (bf16)T[(tc + 2) * 65 + rr], (bf16)T[(tc + 3) * 65 + rr] };
        *(bf16x4*)(dst + dbase + (long)rr * 2048 + tc) = o;
    }
}

// ---------------- fused QKV projection GEMM (z selects Q/K/V), BK=32 DMA staging ----------------
// The thrice-measured 131.5-133 us form: global_load_lds width=16, LDS 33.8 KB, 3 blocks/CU.
// Register-prefetch staging regressed this kernel (138.5 us, 2x bank conflicts) — reverted.
// Wave n-tile remap: col = wn*32 + (nt&1)*16 + (nt>>1)*64 + l16 so the rotary partner
// pair (e, e+64) lives in the same lane as acc[mt][nt] / acc[mt][nt+2].
// z=0: rotary+scale -> QB[bh][s][e]; z=1: rotary -> KB; z=2: +bias -> VT[bh][e][s].
__launch_bounds__(256)
__global__ void qkv_gemm_kernel(const bf16* __restrict__ XQ, const bf16* __restrict__ XK,
                                const bf16* __restrict__ XV,
                                const bf16* __restrict__ WQT, const bf16* __restrict__ WKT,
                                const bf16* __restrict__ WVT,
                                const float* __restrict__ bQ, const float* __restrict__ bK,
                                const float* __restrict__ bV,
                                bf16* __restrict__ QB, bf16* __restrict__ KB,
                                bf16* __restrict__ VT) {
    __shared__ __align__(16) bf16 As[128 * 32];
    __shared__ __align__(16) bf16 Bs[128 * 32];
    __shared__ __align__(16) bf16 Cs[64 * 136];   // V-transpose staging (17 KB)
    const int z = blockIdx.z;
    const bf16* A  = (z == 0) ? XQ  : (z == 1) ? XK  : XV;
    const bf16* Bm = (z == 0) ? WQT : (z == 1) ? WKT : WVT;
    const float* bias = (z == 0) ? bQ : (z == 1) ? bK : bV;

    const int tid = threadIdx.x;
    const int w = tid >> 6, lane = tid & 63;
    const int quad = lane >> 4, l16 = lane & 15;
    const int wm = w & 1, wn = w >> 1;
    const int m_base = blockIdx.x << 7, n_base = blockIdx.y << 7;

    const int srow = lane >> 2;           // 0..15
    const int scol = (lane & 3) << 3;     // 0,8,16,24
    const int ab0 = w * 2, ab1 = w * 2 + 1;
    const bf16* gA0 = A  + (long)(m_base + ab0 * 16 + srow) * 2048 + scol;
    const bf16* gA1 = A  + (long)(m_base + ab1 * 16 + srow) * 2048 + scol;
    const bf16* gB0 = Bm + (long)(n_base + ab0 * 16 + srow) * 2048 + scol;
    const bf16* gB1 = Bm + (long)(n_base + ab1 * 16 + srow) * 2048 + scol;
    bf16* lA0 = &As[ab0 * 512];
    bf16* lA1 = &As[ab1 * 512];
    bf16* lB0 = &Bs[ab0 * 512];
    bf16* lB1 = &Bs[ab1 * 512];

    f32x4 acc[4][4] = {};

    for (int k0 = 0; k0 < 2048; k0 += 32) {
        __builtin_amdgcn_global_load_lds((const __attribute__((address_space(1))) void*)(gA0 + k0),
                                         (__attribute__((address_space(3))) void*)lA0, 16, 0, 0);
        __builtin_amdgcn_global_load_lds((const __attribute__((address_space(1))) void*)(gA1 + k0),
                                         (__attribute__((address_space(3))) void*)lA1, 16, 0, 0);
        __builtin_amdgcn_global_load_lds((const __attribute__((address_space(1))) void*)(gB0 + k0),
                                         (__attribute__((address_space(3))) void*)lB0, 16, 0, 0);
        __builtin_amdgcn_global_load_lds((const __attribute__((address_space(1))) void*)(gB1 + k0),
                                         (__attribute__((address_space(3))) void*)lB1, 16, 0, 0);
        __syncthreads();

        bf16x8 af[4], bfr[4];
#pragma unroll
        for (int mt = 0; mt < 4; mt++)
            af[mt] = *(const bf16x8*)&As[((wm * 64 + mt * 16 + l16) << 5) + (quad << 3)];
#pragma unroll
        for (int nt = 0; nt < 4; nt++) {
            int nrow = wn * 32 + (nt & 1) * 16 + (nt >> 1) * 64 + l16;
            bfr[nt] = *(const bf16x8*)&Bs[(nrow << 5) + (quad << 3)];
        }
#pragma unroll
        for (int mt = 0; mt < 4; mt++)
#pragma unroll
            for (int nt = 0; nt < 4; nt++)
                acc[mt][nt] = __builtin_amdgcn_mfma_f32_16x16x32_bf16(af[mt], bfr[nt], acc[mt][nt], 0, 0, 0);
        __syncthreads();
    }

    const int bq = m_base >> 11;          // batch (whole block same batch)
    const int h  = n_base >> 7;           // head  (N-tile == head width)
    const long obase = ((long)(bq * 16 + h)) << 18;

    if (z <= 1) {
        // rotary epilogue, partner pair in-lane: acc[mt][nt] (e_lo) with acc[mt][nt+2] (e_lo+64)
        bf16* O = (z == 0) ? QB : KB;
        const float scl = (z == 0) ? 0.08838834764831845f : 1.0f;   // 1/sqrt(128) folded into Q
#pragma unroll
        for (int nt = 0; nt < 2; nt++) {
            const int e_lo = wn * 32 + nt * 16 + l16;               // 0..63
            const float bv_lo = bias[n_base + e_lo];
            const float bv_hi = bias[n_base + e_lo + 64];
            const float inv_freq = exp2f((float)e_lo * -0.20762050593046f);  // 10000^(-e/64)
#pragma unroll
            for (int mt = 0; mt < 4; mt++) {
#pragma unroll
                for (int r = 0; r < 4; r++) {
                    int s = (m_base & 2047) + wm * 64 + mt * 16 + quad * 4 + r;
                    float sn, cs;
                    __sincosf((float)s * inv_freq, &sn, &cs);
                    float x0 = acc[mt][nt][r]     + bv_lo;
                    float x1 = acc[mt][nt + 2][r] + bv_hi;
                    O[obase + ((long)s << 7) + e_lo]      = (bf16)((x0 * cs - x1 * sn) * scl);
                    O[obase + ((long)s << 7) + e_lo + 64] = (bf16)((x1 * cs + x0 * sn) * scl);
                }
            }
        }
    } else {
        // V: transpose 128x128 tile to VT[bh][e][s] via LDS, two e-halves of 64
#pragma unroll
        for (int eh = 0; eh < 2; eh++) {
#pragma unroll
            for (int nt2 = 0; nt2 < 2; nt2++) {
                const int nt = eh * 2 + nt2;
                const int e_l = wn * 32 + nt2 * 16 + l16;    // 0..63 local within half
                const float bv = bias[n_base + eh * 64 + e_l];
#pragma unroll
                for (int mt = 0; mt < 4; mt++) {
                    int s0 = wm * 64 + mt * 16 + quad * 4;
                    bf16x4 pk = { (bf16)(acc[mt][nt][0] + bv), (bf16)(acc[mt][nt][1] + bv),
                                  (bf16)(acc[mt][nt][2] + bv), (bf16)(acc[mt][nt][3] + bv) };
                    *(bf16x4*)&Cs[e_l * 136 + s0] = pk;
                }
            }
            __syncthreads();
            {
                const int e_l = tid >> 2;            // 0..63
                const int sq  = (tid & 3) << 5;      // 0,32,64,96
                const int e   = eh * 64 + e_l;
                const long vb = obase + ((long)e << 11) + (m_base & 2047) + sq;
#pragma unroll
                for (int j = 0; j < 4; j++)
                    *(bf16x8*)&VT[vb + j * 8] = *(const bf16x8*)&Cs[e_l * 136 + sq + j * 8];
            }
            __syncthreads();
        }
    }
}

// ---------------- causal flash attention (round-8 form, verified) ----------------
// 1024 single-q-tile blocks: n&7 -> XCD, qt = 31 - n>>5 (heavy first). Register-prefetch
// of kt+1's K/V (4+4 bf16x8). Fixed-max softmax: p = exp(s - 12), cancels in o/l.
__launch_bounds__(256, 3)
__global__ void flash_kernel(const bf16* __restrict__ Q, const bf16* __restrict__ K,
                             const bf16* __restrict__ Vt, bf16* __restrict__ Z) {
    __shared__ __align__(16) bf16 Ks[64 * 136];   // pad 128->136
    __shared__ __align__(16) bf16 Vs[128 * 72];   // pad 64->72, rows = e
    __shared__ __align__(16) bf16 Ps[64 * 72];    // per-wave-private 16-row regions
    const int tid = threadIdx.x, w = tid >> 6, lane = tid & 63;
    const int quad = lane >> 4, l16 = lane & 15;
    const int n = blockIdx.x;
    const int bh = (n & 7) | (((n >> 3) & 3) << 3);   // 0..31, n%8 = bh%8 (XCD-local)
    const int qt = 31 - (n >> 5);                     // heavy first
    const int b = bh >> 4, h = bh & 15;
    const long qk_base = (long)bh << 18;              // bh*2048*128
    const int qbase = qt << 6;
    const float FM = 12.0f;                           // fixed softmax max

    const int kr_row = tid >> 4;          // 0..15   (K: 4 chunks of 16 rows)
    const int kr_col = (tid & 15) << 3;
    const int vr_row = tid >> 3;          // 0..31   (V^T: 4 chunks of 32 e-rows)
    const int vr_col = (tid & 7) << 3;
    const bf16* Kg = K  + qk_base + (long)kr_row * 128 + kr_col;
    const bf16* Vg = Vt + qk_base + (long)vr_row * 2048 + vr_col;

    bf16x8 qf[4];
#pragma unroll
    for (int ks = 0; ks < 4; ks++)
        qf[ks] = *(const bf16x8*)(Q + qk_base + ((long)(qbase + w * 16 + l16) << 7) + ks * 32 + (quad << 3));

    bf16x8 va[4], ka[4], vb2[4], kb[4];
#pragma unroll
    for (int p = 0; p < 4; p++) va[p] = *(const bf16x8*)(Vg + (long)p * 65536);   // p*32 e-rows
#pragma unroll
    for (int p = 0; p < 4; p++) ka[p] = *(const bf16x8*)(Kg + (long)(p * 16) * 128);

    f32x4 o[8] = {};
    float lsum[4] = {0.f, 0.f, 0.f, 0.f};

    for (int kt = 0; kt <= qt; kt++) {
#pragma unroll
        for (int p = 0; p < 4; p++)
            *(bf16x8*)&Vs[(p * 32 + vr_row) * 72 + vr_col] = va[p];
#pragma unroll
        for (int p = 0; p < 4; p++)
            *(bf16x8*)&Ks[(p * 16 + kr_row) * 136 + kr_col] = ka[p];
        if (kt < qt) {
            const long koff = (long)(kt + 1) * 64;
#pragma unroll
            for (int p = 0; p < 4; p++) vb2[p] = *(const bf16x8*)(Vg + (long)p * 65536 + koff);
#pragma unroll
            for (int p = 0; p < 4; p++) kb[p] = *(const bf16x8*)(Kg + (koff + p * 16) * 128);
        }
        __syncthreads();

        f32x4 sc[4] = {};
#pragma unroll
        for (int nt = 0; nt < 4; nt++)
#pragma unroll
            for (int ks = 0; ks < 4; ks++) {
                bf16x8 kf = *(const bf16x8*)&Ks[(nt * 16 + l16) * 136 + ks * 32 + (quad << 3)];
                sc[nt] = __builtin_amdgcn_mfma_f32_16x16x32_bf16(qf[ks], kf, sc[nt], 0, 0, 0);
            }

        if (kt == qt) {   // diagonal tile: causal mask (exp underflows to exact 0)
#pragma unroll
            for (int nt = 0; nt < 4; nt++)
#pragma unroll
                for (int r = 0; r < 4; r++) {
                    int qrow = qbase + w * 16 + quad * 4 + r;
                    int kv = (qt << 6) + nt * 16 + l16;
                    if (kv > qrow) sc[nt][r] = -3.0e38f;
                }
        }

#pragma unroll
        for (int nt = 0; nt < 4; nt++)
#pragma unroll
            for (int r = 0; r < 4; r++) {
                float p = __expf(sc[nt][r] - FM);
                lsum[r] += p;
                Ps[(w * 16 + quad * 4 + r) * 72 + nt * 16 + l16] = (bf16)p;
            }
        // no barrier: Ps region is wave-private; in-wave lgkmcnt orders write->read

#pragma unroll
        for (int kk = 0; kk < 2; kk++) {
            bf16x8 pf = *(const bf16x8*)&Ps[(w * 16 + l16) * 72 + kk * 32 + (quad << 3)];
#pragma unroll
            for (int dt = 0; dt < 8; dt++) {
                bf16x8 vf = *(const bf16x8*)&Vs[(dt * 16 + l16) * 72 + kk * 32 + (quad << 3)];
                o[dt] = __builtin_amdgcn_mfma_f32_16x16x32_bf16(pf, vf, o[dt], 0, 0, 0);
            }
        }
        __syncthreads();   // protect Ks/Vs before next iteration's staging writes

#pragma unroll
        for (int p = 0; p < 4; p++) va[p] = vb2[p];
#pragma unroll
        for (int p = 0; p < 4; p++) ka[p] = kb[p];
    }

#pragma unroll
    for (int r = 0; r < 4; r++) {
        float l = lsum[r];
        l += __shfl_xor(l, 1);
        l += __shfl_xor(l, 2);
        l += __shfl_xor(l, 4);
        l += __shfl_xor(l, 8);
        float inv = 1.f / l;
        int qrow = qbase + w * 16 + quad * 4 + r;
        long zr = ((long)(b * 2048 + qrow) << 11) + h * 128;
#pragma unroll
        for (int dt = 0; dt < 8; dt++)
            Z[zr + dt * 16 + l16] = (bf16)(o[dt][r] * inv);
    }
}

// ---------------- output projection GEMM: BK=32 DMA staging, fp32 out + bias ----------------
__launch_bounds__(256)
__global__ void gemm_o_kernel(const bf16* __restrict__ A, const bf16* __restrict__ Bm,
                              const float* __restrict__ bias, float* __restrict__ Of) {
    __shared__ __align__(16) bf16 As[128 * 32];
    __shared__ __align__(16) bf16 Bs[128 * 32];
    const int tid = threadIdx.x;
    const int w = tid >> 6, lane = tid & 63;
    const int quad = lane >> 4, l16 = lane & 15;
    const int wm = w & 1, wn = w >> 1;
    const int m_base = blockIdx.x << 7, n_base = blockIdx.y << 7;

    const int srow = lane >> 2;
    const int scol = (lane & 3) << 3;
    const int ab0 = w * 2, ab1 = w * 2 + 1;
    const bf16* gA0 = A  + (long)(m_base + ab0 * 16 + srow) * 2048 + scol;
    const bf16* gA1 = A  + (long)(m_base + ab1 * 16 + srow) * 2048 + scol;
    const bf16* gB0 = Bm + (long)(n_base + ab0 * 16 + srow) * 2048 + scol;
    const bf16* gB1 = Bm + (long)(n_base + ab1 * 16 + srow) * 2048 + scol;
    bf16* lA0 = &As[ab0 * 512];
    bf16* lA1 = &As[ab1 * 512];
    bf16* lB0 = &Bs[ab0 * 512];
    bf16* lB1 = &Bs[ab1 * 512];

    f32x4 acc[4][4] = {};

    for (int k0 = 0; k0 < 2048; k0 += 32) {
        __builtin_amdgcn_global_load_lds((const __attribute__((address_space(1))) void*)(gA0 + k0),
                                         (__attribute__((address_space(3))) void*)lA0, 16, 0, 0);
        __builtin_amdgcn_global_load_lds((const __attribute__((address_space(1))) void*)(gA1 + k0),
                                         (__attribute__((address_space(3))) void*)lA1, 16, 0, 0);
        __builtin_amdgcn_global_load_lds((const __attribute__((address_space(1))) void*)(gB0 + k0),
                                         (__attribute__((address_space(3))) void*)lB0, 16, 0, 0);
        __builtin_amdgcn_global_load_lds((const __attribute__((address_space(1))) void*)(gB1 + k0),
                                         (__attribute__((address_space(3))) void*)lB1, 16, 0, 0);
        __syncthreads();

        bf16x8 af[4], bfr[4];
#pragma unroll
        for (int mt = 0; mt < 4; mt++)
            af[mt] = *(const bf16x8*)&As[((wm * 64 + mt * 16 + l16) << 5) + (quad << 3)];
#pragma unroll
        for (int nt = 0; nt < 4; nt++)
            bfr[nt] = *(const bf16x8*)&Bs[((wn * 64 + nt * 16 + l16) << 5) + (quad << 3)];
#pragma unroll
        for (int mt = 0; mt < 4; mt++)
#pragma unroll
            for (int nt = 0; nt < 4; nt++)
                acc[mt][nt] = __builtin_amdgcn_mfma_f32_16x16x32_bf16(af[mt], bfr[nt], acc[mt][nt], 0, 0, 0);
        __syncthreads();
    }

#pragma unroll
    for (int nt = 0; nt < 4; nt++) {
        int col = n_base + wn * 64 + nt * 16 + l16;
        float bv = bias[col];
#pragma unroll
        for (int mt = 0; mt < 4; mt++) {
#pragma unroll
            for (int r = 0; r < 4; r++) {
                int row = m_base + wm * 64 + mt * 16 + quad * 4 + r;
                Of[((long)row << 11) + col] = acc[mt][nt][r] + bv;
            }
        }
    }
}

extern "C" void kernel_launch(void* const* d_in, const int* in_sizes, int n_in,
                              void* d_out, int out_size, void* d_ws, size_t ws_size,
                              hipStream_t stream) {
    (void)in_sizes; (void)n_in; (void)out_size; (void)ws_size;
    const float* qin = (const float*)d_in[0];
    const float* kin = (const float*)d_in[1];
    const float* vin = (const float*)d_in[2];
    const float* WQ  = (const float*)d_in[3];
    const float* WK  = (const float*)d_in[4];
    const float* WV  = (const float*)d_in[5];
    const float* WO  = (const float*)d_in[6];
    const float* bQ  = (const float*)d_in[7];
    const float* bK  = (const float*)d_in[8];
    const float* bV  = (const float*)d_in[9];
    const float* bO  = (const float*)d_in[10];
    float* out = (float*)d_out;

    bf16* ws = (bf16*)d_ws;
    bf16* XQ  = ws + 0L;          // 8,388,608 elems each
    bf16* XK  = ws + 8388608L;
    bf16* XV  = ws + 16777216L;
    bf16* WQT = ws + 25165824L;   // 4,194,304 each
    bf16* WKT = ws + 29360128L;
    bf16* WVT = ws + 33554432L;
    bf16* WOT = ws + 37748736L;
    bf16* QB  = ws + 41943040L;   // [bh][s][e]
    bf16* KB  = ws + 50331648L;   // [bh][s][e]
    bf16* VT  = ws + 58720256L;   // [bh][e][s]   total 67,108,864 elems = 128 MiB
    bf16* Z   = XQ;               // reuse: XQ dead after qkv_gemm dispatch completes

    xcvt_kernel<<<8192, 256, 0, stream>>>(qin, kin, vin, XQ, XK, XV);
    wtr_kernel<<<dim3(1024, 4), 256, 0, stream>>>(WQ, WK, WV, WO, WQT, WKT, WVT, WOT);
    qkv_gemm_kernel<<<dim3(32, 16, 3), 256, 0, stream>>>(XQ, XK, XV, WQT, WKT, WVT,
                                                         bQ, bK, bV, QB, KB, VT);
    flash_kernel<<<1024, 256, 0, stream>>>(QB, KB, VT, Z);
    gemm_o_kernel<<<dim3(32, 16), 256, 0, stream>>>(Z, WOT, bO, out);
}